// Round 8
// baseline (206.533 us; speedup 1.0000x reference)
//
#include <hip/hip_runtime.h>
#include <hip/hip_bf16.h>

// B=8, Ct=256, Cs=128, H=W=32, S=1024, E=256, nH=8, hd=32
typedef unsigned short u16;
typedef unsigned int u32;
typedef __attribute__((ext_vector_type(8))) short short8;
typedef __attribute__((ext_vector_type(4))) float f32x4;
typedef __attribute__((ext_vector_type(4))) unsigned short u16x4;
typedef __attribute__((ext_vector_type(4))) int i32x4;

static __device__ __forceinline__ u16 f2bf(float x) {
  __hip_bfloat16 b = __float2bfloat16(x);
  return *reinterpret_cast<u16*>(&b);
}
static __device__ __forceinline__ u32 fbits(float x) {
  union { float f; u32 u; } v; v.f = x; return v.u;
}
// pack two f32 -> two truncated bf16 in one dword
static __device__ __forceinline__ u32 pk_trunc(float lo, float hi) {
  return __builtin_amdgcn_perm(fbits(hi), fbits(lo), 0x07060302u);
}
// async global->LDS, 16B per lane; dest = lds base (wave-uniform) + lane*16
static __device__ __forceinline__ void gl2lds16(const u16* g, u16* l) {
  __builtin_amdgcn_global_load_lds(
      (const __attribute__((address_space(1))) void*)g,
      (__attribute__((address_space(3))) void*)l, 16, 0, 0);
}

// 1/sqrt(32) * log2(e)  (exp2-based softmax)
#define QSCALE2 (0.17677669529663687f * 1.4426950408889634f)

// ---------------------------------------------------------------------------
// Merged prep + transpose-cast + attn_out zero.
// blocks [0,769): prep weights; [769,1537): xpose; [1537,1569): zero attn_out.
// ---------------------------------------------------------------------------
__global__ __launch_bounds__(256) void prep_xpose(
    const float* __restrict__ in_proj_w, const float* __restrict__ in_proj_b,
    const float* __restrict__ kv_w, const float* __restrict__ fuse_w,
    const float* __restrict__ out_proj_w, const float* __restrict__ out_proj_b,
    const float* __restrict__ gamma, const float* __restrict__ beta,
    const float* __restrict__ mean, const float* __restrict__ var,
    const float* __restrict__ tgt, const float* __restrict__ src,
    u16* __restrict__ WqB, u16* __restrict__ WkvB, u16* __restrict__ M2B,
    float* __restrict__ qbias, float2* __restrict__ bnpk,
    u16* __restrict__ tgtT, u16* __restrict__ srcT,
    float* __restrict__ attn_out) {
  if (blockIdx.x >= 1537) {
    int i = (blockIdx.x - 1537) * 256 + threadIdx.x;
    attn_out[i] = 0.f;
    return;
  }
  if (blockIdx.x < 769) {
    int idx = blockIdx.x * 256 + threadIdx.x;
    if (idx < 65536) {
      WqB[idx] = f2bf(in_proj_w[idx] * QSCALE2);
    } else if (idx < 131072) {
      int i = idx - 65536;
      int m = i >> 7, c = i & 127;
      const float* wrow = in_proj_w + (size_t)(256 + m) * 256;
      float s = 0.f;
      for (int e2 = 0; e2 < 256; ++e2) s += wrow[e2] * kv_w[e2 * 128 + c];
      WkvB[i] = f2bf(s);
    } else if (idx < 196608) {
      int i = idx - 131072;
      int c = i >> 8, e2 = i & 255;
      float s = 0.f;
      for (int e = 0; e < 256; ++e)
        s += fuse_w[c * 256 + e] * out_proj_w[e * 256 + e2];
      M2B[i] = f2bf(s);
    } else if (idx < 196864) {
      int c = idx - 196608;
      float fbv = 0.f;
      for (int e = 0; e < 256; ++e) fbv += fuse_w[c * 256 + e] * out_proj_b[e];
      float inv = gamma[c] * rsqrtf(var[c] + 1e-5f);
      bnpk[c] = make_float2(inv, (fbv - mean[c]) * inv + beta[c]);
      qbias[c] = in_proj_b[c] * QSCALE2;
    }
    return;
  }
  // ---- xpose part ----
  __shared__ u16 tile[64 * 65];
  int i0 = blockIdx.x - 769;
  int b = i0 / 96, rem = i0 % 96;
  int by = rem >> 4, sb = (rem & 15) * 64;
  const float* X;
  u16* XT;
  int C, cb;
  if (by < 4) {
    X = tgt + (size_t)b * 256 * 1024;
    XT = tgtT + (size_t)b * 1024 * 256;
    C = 256;
    cb = by * 64;
  } else {
    X = src + (size_t)b * 128 * 1024;
    XT = srcT + (size_t)b * 1024 * 128;
    C = 128;
    cb = (by - 4) * 64;
  }
  int t = threadIdx.x;
  for (int i = t; i < 4096; i += 256) {
    int c = i >> 6, s = i & 63;
    tile[c * 65 + s] = f2bf(X[(size_t)(cb + c) * 1024 + sb + s]);
  }
  __syncthreads();
  for (int i = t; i < 4096; i += 256) {
    int s = i >> 6, c = i & 63;
    XT[(size_t)(sb + s) * C + cb + c] = tile[c * 65 + s];
  }
}

// ---------------------------------------------------------------------------
// QKV projection, bf16 MFMA, global_load_lds staging, BK=64 (two 32-halves).
// grid (8, 12, 8): my<4 -> Q (WqB, K=256, tgtT); else KV (WkvB, K=128, srcT).
// Tile 64m x 128n; wave = 64m x 32n (acc 4x2).
// ---------------------------------------------------------------------------
__global__ __launch_bounds__(256, 4) void qkv_gemm(
    const u16* __restrict__ tgtT, const u16* __restrict__ srcT,
    const u16* __restrict__ WqB, const u16* __restrict__ WkvB,
    const float* __restrict__ qbias, const float* __restrict__ bkv,
    u16* __restrict__ QB, u16* __restrict__ KB, u16* __restrict__ VB) {
  __shared__ __align__(16) u16 Wl[2][64 * 32];   // 8KB
  __shared__ __align__(16) u16 Xl[2][128 * 32];  // 16KB
  int b = blockIdx.z, my = blockIdx.y, n0 = blockIdx.x * 128;
  bool isQ = my < 4;
  int m0 = isQ ? my * 64 : (my - 4) * 64;
  int Kd = isQ ? 256 : 128;
  const u16* Wp = isQ ? WqB : WkvB;
  const u16* Xp = isQ ? tgtT + (size_t)b * 1024 * 256
                      : srcT + (size_t)b * 1024 * 128;
  int t = threadIdx.x, wave = t >> 6, lane = t & 63;
  int lq = lane & 15, quad = lane >> 4;
  int srow = t >> 2, sseg = t & 3;
  f32x4 acc[4][2];
#pragma unroll
  for (int mt = 0; mt < 4; ++mt)
#pragma unroll
    for (int nt = 0; nt < 2; ++nt) acc[mt][nt] = (f32x4){0.f, 0.f, 0.f, 0.f};

  for (int k0 = 0; k0 < Kd; k0 += 64) {
    __syncthreads();
#pragma unroll
    for (int hh = 0; hh < 2; ++hh) {
      gl2lds16(&Wp[(size_t)(m0 + srow) * Kd + k0 + hh * 32 + sseg * 8],
               &Wl[hh][wave * 512]);
      gl2lds16(&Xp[(size_t)(n0 + srow) * Kd + k0 + hh * 32 + sseg * 8],
               &Xl[hh][wave * 512]);
      gl2lds16(&Xp[(size_t)(n0 + 64 + srow) * Kd + k0 + hh * 32 + sseg * 8],
               &Xl[hh][2048 + wave * 512]);
    }
    __syncthreads();
#pragma unroll
    for (int hh = 0; hh < 2; ++hh) {
      short8 af[4], bf[2];
#pragma unroll
      for (int mt = 0; mt < 4; ++mt)
        af[mt] = *(const short8*)&Wl[hh][(mt * 16 + lq) * 32 + quad * 8];
#pragma unroll
      for (int nt = 0; nt < 2; ++nt)
        bf[nt] = *(const short8*)&Xl[hh][(wave * 32 + nt * 16 + lq) * 32 + quad * 8];
#pragma unroll
      for (int mt = 0; mt < 4; ++mt)
#pragma unroll
        for (int nt = 0; nt < 2; ++nt)
          acc[mt][nt] = __builtin_amdgcn_mfma_f32_16x16x32_bf16(af[mt], bf[nt],
                                                                acc[mt][nt], 0, 0, 0);
    }
  }
  if (isQ) {
#pragma unroll
    for (int mt = 0; mt < 4; ++mt) {
      int e = m0 + mt * 16 + quad * 4;
      f32x4 bi = *(const f32x4*)&qbias[e];
#pragma unroll
      for (int nt = 0; nt < 2; ++nt) {
        int n = n0 + wave * 32 + nt * 16 + lq;
        u16x4 pk;
#pragma unroll
        for (int r = 0; r < 4; ++r) pk[r] = f2bf(acc[mt][nt][r] + bi[r]);
        *(u16x4*)&QB[((size_t)b * 1024 + n) * 256 + e] = pk;
      }
    }
  } else {
#pragma unroll
    for (int mt = 0; mt < 4; ++mt) {
      int m = m0 + mt * 16 + quad * 4;
      f32x4 bi = *(const f32x4*)&bkv[m];
#pragma unroll
      for (int nt = 0; nt < 2; ++nt) {
        int n = n0 + wave * 32 + nt * 16 + lq;
        if (m < 256) {
          int hh = m >> 5, d = m & 31;
          u16x4 pk;
#pragma unroll
          for (int r = 0; r < 4; ++r) pk[r] = f2bf(acc[mt][nt][r] + bi[r]);
          *(u16x4*)&KB[((size_t)(b * 8 + hh) * 1024 + n) * 32 + d] = pk;
        } else {
          int e = m - 256;
#pragma unroll
          for (int r = 0; r < 4; ++r)
            VB[((size_t)b * 256 + e + r) * 1024 + n] = f2bf(acc[mt][nt][r] + bi[r]);
        }
      }
    }
  }
}

// ---------------------------------------------------------------------------
// Fused attention: phase 1 computes row sums (QK streamed direct from global,
// no barriers, any key order); phase 2 stages K/V in 256-key chunks, computes
// P' = exp2(s)*linv (pre-normalized), O += V^T P'^T (MFMA, register-only P),
// and column sums of P' via lq-lane shfl reduction -> attn_out.
// grid (16,8,8)=1024 blocks, 64q, 4 waves x 16q. LDS ~37KB, 4 blocks/CU.
// ---------------------------------------------------------------------------
__global__ __launch_bounds__(256, 4) void attn_fused(
    const u16* __restrict__ QB, const u16* __restrict__ KB,
    const u16* __restrict__ VB, u16* __restrict__ ctxB,
    float* __restrict__ attn_out) {
  __shared__ __align__(16) u16 Klds[256 * 32];     // 16KB, linear key rows
  __shared__ __align__(16) u16 Vlds[2 * 8 * 544];  // 17KB, 2 subchunks x 8 groups
  __shared__ float colsum[1024];                   // 4KB
  int b = blockIdx.z, h = blockIdx.y, q0 = blockIdx.x * 64;
  int t = threadIdx.x, wave = t >> 6, lane = t & 63;
  int lq = lane & 15, quad = lane >> 4;

  const u16* Qb = QB + (size_t)b * 1024 * 256 + h * 32;
  const u16* Kb = KB + (size_t)(b * 8 + h) * 1024 * 32;
  const u16* Vb = VB + (size_t)(b * 256 + h * 32) * 1024;

  for (int i = t; i < 1024; i += 256) colsum[i] = 0.f;

  int myq = q0 + wave * 16 + lq;
  short8 qf = *(const short8*)(Qb + (size_t)myq * 256 + quad * 8);
  const f32x4 zf = (f32x4){0.f, 0.f, 0.f, 0.f};

  // ---------------- Phase 1: row sums (no LDS, no barriers) ----------------
  float lsum = 0.f;
#pragma unroll 2
  for (int c = 0; c < 1024; c += 32) {
    short8 kf0 = *(const short8*)(Kb + (size_t)(c + lq) * 32 + quad * 8);
    short8 kf1 = *(const short8*)(Kb + (size_t)(c + 16 + lq) * 32 + quad * 8);
    f32x4 s0 = __builtin_amdgcn_mfma_f32_16x16x32_bf16(kf0, qf, zf, 0, 0, 0);
    f32x4 s1 = __builtin_amdgcn_mfma_f32_16x16x32_bf16(kf1, qf, zf, 0, 0, 0);
#pragma unroll
    for (int r = 0; r < 4; ++r) lsum += exp2f(s0[r]) + exp2f(s1[r]);
  }
  lsum += __shfl_xor(lsum, 16);
  lsum += __shfl_xor(lsum, 32);
  float linv = 1.f / lsum;  // per-lane: for query lq (of this wave)

  // ---------------- Phase 2: PV + colsum, 256-key chunks ----------------
  int keyA = ((lq >> 2) << 3) | (lq & 3);
  f32x4 O0 = zf, O1 = zf;
  for (int c0 = 0; c0 < 1024; c0 += 256) {
    __syncthreads();
    // K: 256 rows x 64B = 16 calls (4/thread)
#pragma unroll
    for (int i = 0; i < 4; ++i) {
      int cc = wave * 4 + i;
      gl2lds16(Kb + (size_t)(c0 + cc * 16 + (lane >> 2)) * 32 + (lane & 3) * 8,
               &Klds[cc * 512]);
    }
    // V: 2 subchunks x 8 groups of 4 d-rows (16 calls, 4/thread)
#pragma unroll
    for (int i = 0; i < 4; ++i) {
      int g = wave * 4 + i;
      int sub = g >> 3, gr = g & 7;
      int d = gr * 4 + (lane >> 4);
      gl2lds16(Vb + (size_t)d * 1024 + c0 + sub * 128 + (lane & 15) * 8,
               &Vlds[sub * 4352 + gr * 544]);
    }
    __syncthreads();
#pragma unroll
    for (int pair = 0; pair < 8; ++pair) {
      short8 kf0 = *(const short8*)&Klds[(pair * 32 + keyA) * 32 + quad * 8];
      short8 kf1 = *(const short8*)&Klds[(pair * 32 + keyA + 4) * 32 + quad * 8];
      f32x4 s0 = __builtin_amdgcn_mfma_f32_16x16x32_bf16(kf0, qf, zf, 0, 0, 0);
      f32x4 s1 = __builtin_amdgcn_mfma_f32_16x16x32_bf16(kf1, qf, zf, 0, 0, 0);
      float e0[4], e1[4];
#pragma unroll
      for (int r = 0; r < 4; ++r) {
        e0[r] = exp2f(s0[r]) * linv;
        e1[r] = exp2f(s1[r]) * linv;
      }
      // P'^T B-fragment: lane holds keys pair*32 + quad*8 + {0..7} for query lq
      i32x4 pi;
      pi[0] = (int)pk_trunc(e0[0], e0[1]);
      pi[1] = (int)pk_trunc(e0[2], e0[3]);
      pi[2] = (int)pk_trunc(e1[0], e1[1]);
      pi[3] = (int)pk_trunc(e1[2], e1[3]);
      short8 pf = *(short8*)&pi;
      // column sums: reduce p' over the 16 query lanes (lq bits = lane bits 0..3)
#pragma unroll
      for (int j = 0; j < 8; ++j) {
        float v = (j < 4) ? e0[j] : e1[j - 4];
        v += __shfl_xor(v, 1);
        v += __shfl_xor(v, 2);
        v += __shfl_xor(v, 4);
        v += __shfl_xor(v, 8);
        if (lq == 0) atomicAdd(&colsum[c0 + pair * 32 + quad * 8 + j], v);
      }
      // PV
      int sub = pair >> 2, p2 = pair & 3;
      short8 vf0 = *(const short8*)&Vlds[sub * 4352 + (lq >> 2) * 544 +
                                         (lq & 3) * 128 + p2 * 32 + quad * 8];
      short8 vf1 = *(const short8*)&Vlds[sub * 4352 + (4 + (lq >> 2)) * 544 +
                                         (lq & 3) * 128 + p2 * 32 + quad * 8];
      O0 = __builtin_amdgcn_mfma_f32_16x16x32_bf16(vf0, pf, O0, 0, 0, 0);
      O1 = __builtin_amdgcn_mfma_f32_16x16x32_bf16(vf1, pf, O1, 0, 0, 0);
    }
  }

  // ctx write (already normalized): lane holds query lq; rows d = quad*4+r (+16)
  u16x4 pk0, pk1;
#pragma unroll
  for (int r = 0; r < 4; ++r) {
    pk0[r] = f2bf(O0[r]);
    pk1[r] = f2bf(O1[r]);
  }
  u16* crow = ctxB + ((size_t)b * 1024 + myq) * 256 + h * 32 + quad * 4;
  *(u16x4*)crow = pk0;
  *(u16x4*)(crow + 16) = pk1;

  __syncthreads();
  for (int i = t; i < 1024; i += 256)
    atomicAdd(&attn_out[b * 1024 + i], colsum[i] * (1.f / 8192.f));
}

// ---------------------------------------------------------------------------
// Fused out GEMM + BN + SiLU + residual, global_load_lds staging, BK=64.
// Tile 64c x 64s, grid (16,4,8)=512.
// ---------------------------------------------------------------------------
__global__ __launch_bounds__(256, 4) void fused_out(
    const u16* __restrict__ M2B, const u16* __restrict__ ctxB,
    const float* __restrict__ tgt, const float2* __restrict__ bnpk,
    float* __restrict__ y) {
  __shared__ __align__(16) u16 Al[2][64 * 32];  // 8KB
  __shared__ __align__(16) u16 Bl[2][64 * 32];  // 8KB
  int b = blockIdx.z, c0 = blockIdx.y * 64, s0 = blockIdx.x * 64;
  int t = threadIdx.x, wave = t >> 6, lane = t & 63;
  int lq = lane & 15, quad = lane >> 4;
  int srow = t >> 2, sseg = t & 3;
  f32x4 acc[4];
#pragma unroll
  for (int mt = 0; mt < 4; ++mt) acc[mt] = (f32x4){0.f, 0.f, 0.f, 0.f};

  for (int k0 = 0; k0 < 256; k0 += 64) {
    __syncthreads();
#pragma unroll
    for (int hh = 0; hh < 2; ++hh) {
      gl2lds16(&M2B[(size_t)(c0 + srow) * 256 + k0 + hh * 32 + sseg * 8],
               &Al[hh][wave * 512]);
      gl2lds16(&ctxB[((size_t)b * 1024 + s0 + srow) * 256 + k0 + hh * 32 + sseg * 8],
               &Bl[hh][wave * 512]);
    }
    __syncthreads();
#pragma unroll
    for (int hh = 0; hh < 2; ++hh) {
      short8 bf = *(const short8*)&Bl[hh][(wave * 16 + lq) * 32 + quad * 8];
      short8 af[4];
#pragma unroll
      for (int mt = 0; mt < 4; ++mt)
        af[mt] = *(const short8*)&Al[hh][(mt * 16 + lq) * 32 + quad * 8];
#pragma unroll
      for (int mt = 0; mt < 4; ++mt)
        acc[mt] = __builtin_amdgcn_mfma_f32_16x16x32_bf16(af[mt], bf, acc[mt], 0, 0, 0);
    }
  }
  int s = s0 + wave * 16 + lq;
#pragma unroll
  for (int mt = 0; mt < 4; ++mt) {
#pragma unroll
    for (int r = 0; r < 4; ++r) {
      int c = c0 + mt * 16 + quad * 4 + r;
      float2 p = bnpk[c];
      float bn = acc[mt][r] * p.x + p.y;
      float sig = 1.f / (1.f + __expf(-bn));
      size_t idx = ((size_t)b * 256 + c) * 1024 + s;
      y[idx] = tgt[idx] + bn * sig;
    }
  }
}

// ---------------------------------------------------------------------------
extern "C" void kernel_launch(void* const* d_in, const int* in_sizes, int n_in,
                              void* d_out, int out_size, void* d_ws, size_t ws_size,
                              hipStream_t stream) {
  const float* tgt = (const float*)d_in[0];
  const float* src = (const float*)d_in[1];
  const float* kv_w = (const float*)d_in[2];
  const float* in_proj_w = (const float*)d_in[3];
  const float* in_proj_b = (const float*)d_in[4];
  const float* out_proj_w = (const float*)d_in[5];
  const float* out_proj_b = (const float*)d_in[6];
  const float* fuse_w = (const float*)d_in[7];
  const float* bn_gamma = (const float*)d_in[8];
  const float* bn_beta = (const float*)d_in[9];
  const float* bn_mean = (const float*)d_in[10];
  const float* bn_var = (const float*)d_in[11];

  char* W = (char*)d_ws;
  u16* WqB = (u16*)W;                      // 128KB
  u16* WkvB = (u16*)(W + 131072);          // 128KB
  u16* M2B = (u16*)(W + 262144);           // 128KB
  float* qbias = (float*)(W + 393216);     // 1KB
  float2* bnpk = (float2*)(W + 394240);    // 2KB
  u16* tgtT = (u16*)(W + 397312);          // 4MB (B,S,256) bf16
  u16* srcT = tgtT + 2097152;              // 2MB (B,S,128) bf16
  u16* QB = srcT + 1048576;                // 4MB (B,S,E)
  u16* KB = QB + 2097152;                  // 4MB (B,nH,S,hd)
  u16* VB = KB + 2097152;                  // 4MB (B,E,S)
  u16* ctxB = VB + 2097152;                // 4MB (B,S,E)

  float* y = (float*)d_out;
  float* attn_out = y + 2097152;

  prep_xpose<<<1569, 256, 0, stream>>>(in_proj_w, in_proj_b, kv_w, fuse_w,
                                       out_proj_w, out_proj_b, bn_gamma, bn_beta,
                                       bn_mean, bn_var, tgt, src,
                                       WqB, WkvB, M2B, qbias, bnpk, tgtT, srcT,
                                       attn_out);
  qkv_gemm<<<dim3(8, 12, 8), 256, 0, stream>>>(tgtT, srcT, WqB, WkvB, qbias,
                                               in_proj_b + 256, QB, KB, VB);
  attn_fused<<<dim3(16, 8, 8), 256, 0, stream>>>(QB, KB, VB, ctxB, attn_out);
  fused_out<<<dim3(16, 4, 8), 256, 0, stream>>>(M2B, ctxB, tgt, bnpk, y);
}

// Round 9
// 173.534 us; speedup vs baseline: 1.1902x; 1.1902x over previous
//
#include <hip/hip_runtime.h>
#include <hip/hip_bf16.h>

// B=8, Ct=256, Cs=128, H=W=32, S=1024, E=256, nH=8, hd=32
typedef unsigned short u16;
typedef unsigned int u32;
typedef __attribute__((ext_vector_type(8))) short short8;
typedef __attribute__((ext_vector_type(4))) float f32x4;
typedef __attribute__((ext_vector_type(4))) unsigned short u16x4;
typedef __attribute__((ext_vector_type(4))) int i32x4;

static __device__ __forceinline__ u16 f2bf(float x) {
  __hip_bfloat16 b = __float2bfloat16(x);
  return *reinterpret_cast<u16*>(&b);
}
static __device__ __forceinline__ u32 fbits(float x) {
  union { float f; u32 u; } v; v.f = x; return v.u;
}
// pack two f32 -> two truncated bf16 in one dword
static __device__ __forceinline__ u32 pk_trunc(float lo, float hi) {
  return __builtin_amdgcn_perm(fbits(hi), fbits(lo), 0x07060302u);
}
// async global->LDS, 16B per lane; dest = lds base (wave-uniform) + lane*16
static __device__ __forceinline__ void gl2lds16(const u16* g, u16* l) {
  __builtin_amdgcn_global_load_lds(
      (const __attribute__((address_space(1))) void*)g,
      (__attribute__((address_space(3))) void*)l, 16, 0, 0);
}

// 1/sqrt(32) * log2(e)  (exp2-based softmax)
#define QSCALE2 (0.17677669529663687f * 1.4426950408889634f)

// ---------------------------------------------------------------------------
// Merged prep + transpose-cast + attn_out zero.
// blocks [0,769): prep weights; [769,1537): xpose; [1537,1569): zero attn_out.
// ---------------------------------------------------------------------------
__global__ __launch_bounds__(256) void prep_xpose(
    const float* __restrict__ in_proj_w, const float* __restrict__ in_proj_b,
    const float* __restrict__ kv_w, const float* __restrict__ fuse_w,
    const float* __restrict__ out_proj_w, const float* __restrict__ out_proj_b,
    const float* __restrict__ gamma, const float* __restrict__ beta,
    const float* __restrict__ mean, const float* __restrict__ var,
    const float* __restrict__ tgt, const float* __restrict__ src,
    u16* __restrict__ WqB, u16* __restrict__ WkvB, u16* __restrict__ M2B,
    float* __restrict__ qbias, float2* __restrict__ bnpk,
    u16* __restrict__ tgtT, u16* __restrict__ srcT,
    float* __restrict__ attn_out) {
  if (blockIdx.x >= 1537) {
    int i = (blockIdx.x - 1537) * 256 + threadIdx.x;
    attn_out[i] = 0.f;
    return;
  }
  if (blockIdx.x < 769) {
    int idx = blockIdx.x * 256 + threadIdx.x;
    if (idx < 65536) {
      WqB[idx] = f2bf(in_proj_w[idx] * QSCALE2);
    } else if (idx < 131072) {
      int i = idx - 65536;
      int m = i >> 7, c = i & 127;
      const float* wrow = in_proj_w + (size_t)(256 + m) * 256;
      float s = 0.f;
      for (int e2 = 0; e2 < 256; ++e2) s += wrow[e2] * kv_w[e2 * 128 + c];
      WkvB[i] = f2bf(s);
    } else if (idx < 196608) {
      int i = idx - 131072;
      int c = i >> 8, e2 = i & 255;
      float s = 0.f;
      for (int e = 0; e < 256; ++e)
        s += fuse_w[c * 256 + e] * out_proj_w[e * 256 + e2];
      M2B[i] = f2bf(s);
    } else if (idx < 196864) {
      int c = idx - 196608;
      float fbv = 0.f;
      for (int e = 0; e < 256; ++e) fbv += fuse_w[c * 256 + e] * out_proj_b[e];
      float inv = gamma[c] * rsqrtf(var[c] + 1e-5f);
      bnpk[c] = make_float2(inv, (fbv - mean[c]) * inv + beta[c]);
      qbias[c] = in_proj_b[c] * QSCALE2;
    }
    return;
  }
  // ---- xpose part ----
  __shared__ u16 tile[64 * 65];
  int i0 = blockIdx.x - 769;
  int b = i0 / 96, rem = i0 % 96;
  int by = rem >> 4, sb = (rem & 15) * 64;
  const float* X;
  u16* XT;
  int C, cb;
  if (by < 4) {
    X = tgt + (size_t)b * 256 * 1024;
    XT = tgtT + (size_t)b * 1024 * 256;
    C = 256;
    cb = by * 64;
  } else {
    X = src + (size_t)b * 128 * 1024;
    XT = srcT + (size_t)b * 1024 * 128;
    C = 128;
    cb = (by - 4) * 64;
  }
  int t = threadIdx.x;
  for (int i = t; i < 4096; i += 256) {
    int c = i >> 6, s = i & 63;
    tile[c * 65 + s] = f2bf(X[(size_t)(cb + c) * 1024 + sb + s]);
  }
  __syncthreads();
  for (int i = t; i < 4096; i += 256) {
    int s = i >> 6, c = i & 63;
    XT[(size_t)(sb + s) * C + cb + c] = tile[c * 65 + s];
  }
}

// ---------------------------------------------------------------------------
// QKV projection, bf16 MFMA, double-buffered global_load_lds staging (BK=32,
// one barrier per chunk, loads for chunk i+1 in flight during compute of i).
// grid (8, 12, 8): my<4 -> Q (WqB, K=256, tgtT); else KV (WkvB, K=128, srcT).
// Tile 64m x 128n; wave = 64m x 32n (acc 4x2). LDS 24KB.
// ---------------------------------------------------------------------------
__global__ __launch_bounds__(256, 4) void qkv_gemm(
    const u16* __restrict__ tgtT, const u16* __restrict__ srcT,
    const u16* __restrict__ WqB, const u16* __restrict__ WkvB,
    const float* __restrict__ qbias, const float* __restrict__ bkv,
    u16* __restrict__ QB, u16* __restrict__ KB, u16* __restrict__ VB) {
  __shared__ __align__(16) u16 Wl[2][64 * 32];   // 8KB
  __shared__ __align__(16) u16 Xl[2][128 * 32];  // 16KB
  int b = blockIdx.z, my = blockIdx.y, n0 = blockIdx.x * 128;
  bool isQ = my < 4;
  int m0 = isQ ? my * 64 : (my - 4) * 64;
  int Kd = isQ ? 256 : 128;
  const u16* Wp = isQ ? WqB : WkvB;
  const u16* Xp = isQ ? tgtT + (size_t)b * 1024 * 256
                      : srcT + (size_t)b * 1024 * 128;
  int t = threadIdx.x, wave = t >> 6, lane = t & 63;
  int lq = lane & 15, quad = lane >> 4;
  int srow = t >> 2, sseg = t & 3;
  f32x4 acc[4][2];
#pragma unroll
  for (int mt = 0; mt < 4; ++mt)
#pragma unroll
    for (int nt = 0; nt < 2; ++nt) acc[mt][nt] = (f32x4){0.f, 0.f, 0.f, 0.f};

  const int NC = Kd >> 5;  // 8 (Q) or 4 (KV)
  // prologue: stage chunk 0 into buffer 0
  gl2lds16(&Wp[(size_t)(m0 + srow) * Kd + sseg * 8], &Wl[0][wave * 512]);
  gl2lds16(&Xp[(size_t)(n0 + srow) * Kd + sseg * 8], &Xl[0][wave * 512]);
  gl2lds16(&Xp[(size_t)(n0 + 64 + srow) * Kd + sseg * 8], &Xl[0][2048 + wave * 512]);
  __syncthreads();
  for (int ci = 0; ci < NC; ++ci) {
    int cur = ci & 1;
    if (ci + 1 < NC) {
      int nb = cur ^ 1, k0 = (ci + 1) << 5;
      gl2lds16(&Wp[(size_t)(m0 + srow) * Kd + k0 + sseg * 8], &Wl[nb][wave * 512]);
      gl2lds16(&Xp[(size_t)(n0 + srow) * Kd + k0 + sseg * 8], &Xl[nb][wave * 512]);
      gl2lds16(&Xp[(size_t)(n0 + 64 + srow) * Kd + k0 + sseg * 8],
               &Xl[nb][2048 + wave * 512]);
    }
    short8 af[4], bf[2];
#pragma unroll
    for (int mt = 0; mt < 4; ++mt)
      af[mt] = *(const short8*)&Wl[cur][(mt * 16 + lq) * 32 + quad * 8];
#pragma unroll
    for (int nt = 0; nt < 2; ++nt)
      bf[nt] = *(const short8*)&Xl[cur][(wave * 32 + nt * 16 + lq) * 32 + quad * 8];
#pragma unroll
    for (int mt = 0; mt < 4; ++mt)
#pragma unroll
      for (int nt = 0; nt < 2; ++nt)
        acc[mt][nt] = __builtin_amdgcn_mfma_f32_16x16x32_bf16(af[mt], bf[nt],
                                                              acc[mt][nt], 0, 0, 0);
    __syncthreads();
  }
  if (isQ) {
#pragma unroll
    for (int mt = 0; mt < 4; ++mt) {
      int e = m0 + mt * 16 + quad * 4;
      f32x4 bi = *(const f32x4*)&qbias[e];
#pragma unroll
      for (int nt = 0; nt < 2; ++nt) {
        int n = n0 + wave * 32 + nt * 16 + lq;
        u16x4 pk;
#pragma unroll
        for (int r = 0; r < 4; ++r) pk[r] = f2bf(acc[mt][nt][r] + bi[r]);
        *(u16x4*)&QB[((size_t)b * 1024 + n) * 256 + e] = pk;
      }
    }
  } else {
#pragma unroll
    for (int mt = 0; mt < 4; ++mt) {
      int m = m0 + mt * 16 + quad * 4;
      f32x4 bi = *(const f32x4*)&bkv[m];
#pragma unroll
      for (int nt = 0; nt < 2; ++nt) {
        int n = n0 + wave * 32 + nt * 16 + lq;
        if (m < 256) {
          int hh = m >> 5, d = m & 31;
          u16x4 pk;
#pragma unroll
          for (int r = 0; r < 4; ++r) pk[r] = f2bf(acc[mt][nt][r] + bi[r]);
          *(u16x4*)&KB[((size_t)(b * 8 + hh) * 1024 + n) * 32 + d] = pk;
        } else {
          int e = m - 256;
#pragma unroll
          for (int r = 0; r < 4; ++r)
            VB[((size_t)b * 256 + e + r) * 1024 + n] = f2bf(acc[mt][nt][r] + bi[r]);
        }
      }
    }
  }
}

// ---------------------------------------------------------------------------
// Attention pass A (register-P, transposed scores, R7 math) with
// double-buffered K/V staging: one barrier per 128-key chunk.
// grid (16,8,8)=1024 blocks, 64q, 4 waves x 16q. LDS 33KB -> 4 blocks/CU.
// ---------------------------------------------------------------------------
__global__ __launch_bounds__(256, 4) void attn_passA(
    const u16* __restrict__ QB, const u16* __restrict__ KB,
    const u16* __restrict__ VB, u16* __restrict__ ctxB,
    float* __restrict__ linv_ws) {
  __shared__ __align__(16) u16 Klds[2][128 * 32];  // 16KB, linear rows
  __shared__ __align__(16) u16 Vlds[2][8 * 544];   // 17KB
  int b = blockIdx.z, h = blockIdx.y, q0 = blockIdx.x * 64;
  int t = threadIdx.x, wave = t >> 6, lane = t & 63;
  int lq = lane & 15, quad = lane >> 4;
  int srow = t >> 2, sseg = t & 3;

  const u16* Qb = QB + (size_t)b * 1024 * 256 + h * 32;
  const u16* Kb = KB + (size_t)(b * 8 + h) * 1024 * 32;
  const u16* Vb = VB + (size_t)(b * 256 + h * 32) * 1024;

  int myq = q0 + wave * 16 + lq;
  short8 qf = *(const short8*)(Qb + (size_t)myq * 256 + quad * 8);

  const f32x4 zf = (f32x4){0.f, 0.f, 0.f, 0.f};
  f32x4 O0 = zf, O1 = zf;
  float lsum = 0.f;
  int keyA = ((lq >> 2) << 3) | (lq & 3);
  int vg0 = lane >> 4, vpart = (lane & 15) * 8;

  // prologue: stage chunk 0 into buffer 0
  gl2lds16(Kb + (size_t)srow * 32 + sseg * 8, &Klds[0][wave * 512]);
  gl2lds16(Kb + (size_t)(64 + srow) * 32 + sseg * 8, &Klds[0][2048 + wave * 512]);
#pragma unroll
  for (int c = 0; c < 2; ++c) {
    int g = c * 4 + wave;
    gl2lds16(Vb + (size_t)(g * 4 + vg0) * 1024 + vpart, &Vlds[0][g * 544]);
  }
  __syncthreads();

  for (int ci = 0; ci < 8; ++ci) {
    int cur = ci & 1;
    if (ci < 7) {
      int nb = cur ^ 1, c0 = (ci + 1) << 7;
      gl2lds16(Kb + (size_t)(c0 + srow) * 32 + sseg * 8, &Klds[nb][wave * 512]);
      gl2lds16(Kb + (size_t)(c0 + 64 + srow) * 32 + sseg * 8,
               &Klds[nb][2048 + wave * 512]);
#pragma unroll
      for (int c = 0; c < 2; ++c) {
        int g = c * 4 + wave;
        gl2lds16(Vb + (size_t)(g * 4 + vg0) * 1024 + c0 + vpart, &Vlds[nb][g * 544]);
      }
    }
#pragma unroll
    for (int pair = 0; pair < 4; ++pair) {
      short8 kf0 = *(const short8*)&Klds[cur][(pair * 32 + keyA) * 32 + quad * 8];
      short8 kf1 = *(const short8*)&Klds[cur][(pair * 32 + keyA + 4) * 32 + quad * 8];
      f32x4 s0 = __builtin_amdgcn_mfma_f32_16x16x32_bf16(kf0, qf, zf, 0, 0, 0);
      f32x4 s1 = __builtin_amdgcn_mfma_f32_16x16x32_bf16(kf1, qf, zf, 0, 0, 0);
      f32x4 e0, e1;
#pragma unroll
      for (int r = 0; r < 4; ++r) {
        e0[r] = exp2f(s0[r]);
        e1[r] = exp2f(s1[r]);
      }
      lsum += (e0[0] + e0[1]) + (e0[2] + e0[3]) +
              (e1[0] + e1[1]) + (e1[2] + e1[3]);
      i32x4 pi;
      pi[0] = (int)pk_trunc(e0[0], e0[1]);
      pi[1] = (int)pk_trunc(e0[2], e0[3]);
      pi[2] = (int)pk_trunc(e1[0], e1[1]);
      pi[3] = (int)pk_trunc(e1[2], e1[3]);
      short8 pf = *(short8*)&pi;
      short8 vf0 = *(const short8*)&Vlds[cur][((lq >> 2) * 544) + (lq & 3) * 128 +
                                             pair * 32 + quad * 8];
      short8 vf1 = *(const short8*)&Vlds[cur][((4 + (lq >> 2)) * 544) +
                                             (lq & 3) * 128 + pair * 32 + quad * 8];
      O0 = __builtin_amdgcn_mfma_f32_16x16x32_bf16(vf0, pf, O0, 0, 0, 0);
      O1 = __builtin_amdgcn_mfma_f32_16x16x32_bf16(vf1, pf, O1, 0, 0, 0);
    }
    __syncthreads();
  }

  lsum += __shfl_xor(lsum, 16);
  lsum += __shfl_xor(lsum, 32);
  float linv = 1.f / lsum;

  u16x4 pk0, pk1;
#pragma unroll
  for (int r = 0; r < 4; ++r) {
    pk0[r] = f2bf(O0[r] * linv);
    pk1[r] = f2bf(O1[r] * linv);
  }
  u16* crow = ctxB + ((size_t)b * 1024 + myq) * 256 + h * 32 + quad * 4;
  *(u16x4*)crow = pk0;
  *(u16x4*)(crow + 16) = pk1;
  if (quad == 0) linv_ws[(size_t)(b * 8 + h) * 1024 + myq] = linv;
}

// ---------------------------------------------------------------------------
// Colsum (attention map): recompute QK untransposed, p=exp2(s)*linv, reduce
// over queries. Double-buffered K staging, one barrier per chunk.
// grid (8,8,8)=512 blocks, 128q each, 4 waves x 32q. LDS 20KB.
// ---------------------------------------------------------------------------
__global__ __launch_bounds__(256, 4) void colsum_kernel(
    const u16* __restrict__ QB, const u16* __restrict__ KB,
    const float* __restrict__ linv_ws, float* __restrict__ attn_out) {
  __shared__ __align__(16) u16 Klds[2][128 * 32];  // 16KB
  __shared__ float colsum[1024];
  int b = blockIdx.z, h = blockIdx.y, q0 = blockIdx.x * 128;
  int t = threadIdx.x, wave = t >> 6, lane = t & 63;
  int lq = lane & 15, quad = lane >> 4;
  int srow = t >> 2, sseg = t & 3;

  const u16* Qb = QB + (size_t)b * 1024 * 256 + h * 32;
  const u16* Kb = KB + (size_t)(b * 8 + h) * 1024 * 32;
  const float* lvp = linv_ws + (size_t)(b * 8 + h) * 1024 + q0 + wave * 32;

  short8 qf2[2];
  f32x4 lv[2];
#pragma unroll
  for (int mt = 0; mt < 2; ++mt) {
    qf2[mt] = *(const short8*)(Qb + (size_t)(q0 + wave * 32 + mt * 16 + lq) * 256 + quad * 8);
    lv[mt] = *(const f32x4*)&lvp[mt * 16 + quad * 4];
  }
  for (int i = t; i < 1024; i += 256) colsum[i] = 0.f;
  const f32x4 zf = (f32x4){0.f, 0.f, 0.f, 0.f};

  gl2lds16(Kb + (size_t)srow * 32 + sseg * 8, &Klds[0][wave * 512]);
  gl2lds16(Kb + (size_t)(64 + srow) * 32 + sseg * 8, &Klds[0][2048 + wave * 512]);
  __syncthreads();
  for (int ci = 0; ci < 8; ++ci) {
    int cur = ci & 1;
    if (ci < 7) {
      int nb = cur ^ 1, c0 = (ci + 1) << 7;
      gl2lds16(Kb + (size_t)(c0 + srow) * 32 + sseg * 8, &Klds[nb][wave * 512]);
      gl2lds16(Kb + (size_t)(c0 + 64 + srow) * 32 + sseg * 8,
               &Klds[nb][2048 + wave * 512]);
    }
    int c0 = ci << 7;
#pragma unroll
    for (int nt = 0; nt < 8; ++nt) {
      short8 kf = *(const short8*)&Klds[cur][(nt * 16 + lq) * 32 + quad * 8];
      float cs = 0.f;
#pragma unroll
      for (int mt = 0; mt < 2; ++mt) {
        f32x4 s = __builtin_amdgcn_mfma_f32_16x16x32_bf16(qf2[mt], kf, zf, 0, 0, 0);
        cs += exp2f(s[0]) * lv[mt][0] + exp2f(s[1]) * lv[mt][1] +
              exp2f(s[2]) * lv[mt][2] + exp2f(s[3]) * lv[mt][3];
      }
      cs += __shfl_xor(cs, 16);
      cs += __shfl_xor(cs, 32);
      if (quad == 0) atomicAdd(&colsum[c0 + nt * 16 + lq], cs);
    }
    __syncthreads();
  }
  for (int i = t; i < 1024; i += 256)
    atomicAdd(&attn_out[b * 1024 + i], colsum[i] * (1.f / 8192.f));
}

// ---------------------------------------------------------------------------
// Fused out GEMM + BN + SiLU + residual, double-buffered staging, BK=32.
// Tile 64c x 64s, grid (16,4,8)=512. LDS 16KB.
// ---------------------------------------------------------------------------
__global__ __launch_bounds__(256, 4) void fused_out(
    const u16* __restrict__ M2B, const u16* __restrict__ ctxB,
    const float* __restrict__ tgt, const float2* __restrict__ bnpk,
    float* __restrict__ y) {
  __shared__ __align__(16) u16 Al[2][64 * 32];  // 8KB
  __shared__ __align__(16) u16 Bl[2][64 * 32];  // 8KB
  int b = blockIdx.z, c0 = blockIdx.y * 64, s0 = blockIdx.x * 64;
  int t = threadIdx.x, wave = t >> 6, lane = t & 63;
  int lq = lane & 15, quad = lane >> 4;
  int srow = t >> 2, sseg = t & 3;
  f32x4 acc[4];
#pragma unroll
  for (int mt = 0; mt < 4; ++mt) acc[mt] = (f32x4){0.f, 0.f, 0.f, 0.f};

  const u16* Bp = ctxB + ((size_t)b * 1024 + s0) * 256;
  gl2lds16(&M2B[(size_t)(c0 + srow) * 256 + sseg * 8], &Al[0][wave * 512]);
  gl2lds16(&Bp[(size_t)srow * 256 + sseg * 8], &Bl[0][wave * 512]);
  __syncthreads();
  for (int ci = 0; ci < 8; ++ci) {
    int cur = ci & 1;
    if (ci < 7) {
      int nb = cur ^ 1, k0 = (ci + 1) << 5;
      gl2lds16(&M2B[(size_t)(c0 + srow) * 256 + k0 + sseg * 8], &Al[nb][wave * 512]);
      gl2lds16(&Bp[(size_t)srow * 256 + k0 + sseg * 8], &Bl[nb][wave * 512]);
    }
    short8 bf = *(const short8*)&Bl[cur][(wave * 16 + lq) * 32 + quad * 8];
    short8 af[4];
#pragma unroll
    for (int mt = 0; mt < 4; ++mt)
      af[mt] = *(const short8*)&Al[cur][(mt * 16 + lq) * 32 + quad * 8];
#pragma unroll
    for (int mt = 0; mt < 4; ++mt)
      acc[mt] = __builtin_amdgcn_mfma_f32_16x16x32_bf16(af[mt], bf, acc[mt], 0, 0, 0);
    __syncthreads();
  }
  int s = s0 + wave * 16 + lq;
#pragma unroll
  for (int mt = 0; mt < 4; ++mt) {
#pragma unroll
    for (int r = 0; r < 4; ++r) {
      int c = c0 + mt * 16 + quad * 4 + r;
      float2 p = bnpk[c];
      float bn = acc[mt][r] * p.x + p.y;
      float sig = 1.f / (1.f + __expf(-bn));
      size_t idx = ((size_t)b * 256 + c) * 1024 + s;
      y[idx] = tgt[idx] + bn * sig;
    }
  }
}

// ---------------------------------------------------------------------------
extern "C" void kernel_launch(void* const* d_in, const int* in_sizes, int n_in,
                              void* d_out, int out_size, void* d_ws, size_t ws_size,
                              hipStream_t stream) {
  const float* tgt = (const float*)d_in[0];
  const float* src = (const float*)d_in[1];
  const float* kv_w = (const float*)d_in[2];
  const float* in_proj_w = (const float*)d_in[3];
  const float* in_proj_b = (const float*)d_in[4];
  const float* out_proj_w = (const float*)d_in[5];
  const float* out_proj_b = (const float*)d_in[6];
  const float* fuse_w = (const float*)d_in[7];
  const float* bn_gamma = (const float*)d_in[8];
  const float* bn_beta = (const float*)d_in[9];
  const float* bn_mean = (const float*)d_in[10];
  const float* bn_var = (const float*)d_in[11];

  char* W = (char*)d_ws;
  u16* WqB = (u16*)W;                      // 128KB
  u16* WkvB = (u16*)(W + 131072);          // 128KB
  u16* M2B = (u16*)(W + 262144);           // 128KB
  float* qbias = (float*)(W + 393216);     // 1KB
  float2* bnpk = (float2*)(W + 394240);    // 2KB
  u16* tgtT = (u16*)(W + 397312);          // 4MB (B,S,256) bf16
  u16* srcT = tgtT + 2097152;              // 2MB (B,S,128) bf16
  u16* QB = srcT + 1048576;                // 4MB (B,S,E)
  u16* KB = QB + 2097152;                  // 4MB (B,nH,S,hd)
  u16* VB = KB + 2097152;                  // 4MB (B,E,S)
  u16* ctxB = VB + 2097152;                // 4MB (B,S,E)
  float* linv_ws = (float*)(ctxB + 2097152);  // 256KB (B,nH,S)

  float* y = (float*)d_out;
  float* attn_out = y + 2097152;

  prep_xpose<<<1569, 256, 0, stream>>>(in_proj_w, in_proj_b, kv_w, fuse_w,
                                       out_proj_w, out_proj_b, bn_gamma, bn_beta,
                                       bn_mean, bn_var, tgt, src,
                                       WqB, WkvB, M2B, qbias, bnpk, tgtT, srcT,
                                       attn_out);
  qkv_gemm<<<dim3(8, 12, 8), 256, 0, stream>>>(tgtT, srcT, WqB, WkvB, qbias,
                                               in_proj_b + 256, QB, KB, VB);
  attn_passA<<<dim3(16, 8, 8), 256, 0, stream>>>(QB, KB, VB, ctxB, linv_ws);
  colsum_kernel<<<dim3(8, 8, 8), 256, 0, stream>>>(QB, KB, linv_ws, attn_out);
  fused_out<<<dim3(16, 4, 8), 256, 0, stream>>>(M2B, ctxB, tgt, bnpk, y);
}

// Round 10
// 171.927 us; speedup vs baseline: 1.2013x; 1.0093x over previous
//
#include <hip/hip_runtime.h>
#include <hip/hip_bf16.h>

// B=8, Ct=256, Cs=128, H=W=32, S=1024, E=256, nH=8, hd=32
typedef unsigned short u16;
typedef unsigned int u32;
typedef __attribute__((ext_vector_type(8))) short short8;
typedef __attribute__((ext_vector_type(4))) float f32x4;
typedef __attribute__((ext_vector_type(4))) unsigned short u16x4;
typedef __attribute__((ext_vector_type(4))) int i32x4;

static __device__ __forceinline__ u16 f2bf(float x) {
  __hip_bfloat16 b = __float2bfloat16(x);
  return *reinterpret_cast<u16*>(&b);
}
static __device__ __forceinline__ u32 fbits(float x) {
  union { float f; u32 u; } v; v.f = x; return v.u;
}
// pack two f32 -> two truncated bf16 in one dword
static __device__ __forceinline__ u32 pk_trunc(float lo, float hi) {
  return __builtin_amdgcn_perm(fbits(hi), fbits(lo), 0x07060302u);
}
// async global->LDS, 16B per lane; dest = lds base (wave-uniform) + lane*16
static __device__ __forceinline__ void gl2lds16(const u16* g, u16* l) {
  __builtin_amdgcn_global_load_lds(
      (const __attribute__((address_space(1))) void*)g,
      (__attribute__((address_space(3))) void*)l, 16, 0, 0);
}

// 1/sqrt(32) * log2(e)  (exp2-based softmax)
#define QSCALE2 (0.17677669529663687f * 1.4426950408889634f)

// ---------------------------------------------------------------------------
// Merged prep + transpose-cast + attn_out zero.
// blocks [0,769): prep weights; [769,1537): xpose; [1537,1569): zero attn_out.
// ---------------------------------------------------------------------------
__global__ __launch_bounds__(256) void prep_xpose(
    const float* __restrict__ in_proj_w, const float* __restrict__ in_proj_b,
    const float* __restrict__ kv_w, const float* __restrict__ fuse_w,
    const float* __restrict__ out_proj_w, const float* __restrict__ out_proj_b,
    const float* __restrict__ gamma, const float* __restrict__ beta,
    const float* __restrict__ mean, const float* __restrict__ var,
    const float* __restrict__ tgt, const float* __restrict__ src,
    u16* __restrict__ WqB, u16* __restrict__ WkvB, u16* __restrict__ M2B,
    float* __restrict__ qbias, float2* __restrict__ bnpk,
    u16* __restrict__ tgtT, u16* __restrict__ srcT,
    float* __restrict__ attn_out) {
  if (blockIdx.x >= 1537) {
    int i = (blockIdx.x - 1537) * 256 + threadIdx.x;
    attn_out[i] = 0.f;
    return;
  }
  if (blockIdx.x < 769) {
    int idx = blockIdx.x * 256 + threadIdx.x;
    if (idx < 65536) {
      WqB[idx] = f2bf(in_proj_w[idx] * QSCALE2);
    } else if (idx < 131072) {
      int i = idx - 65536;
      int m = i >> 7, c = i & 127;
      const float* wrow = in_proj_w + (size_t)(256 + m) * 256;
      float s = 0.f;
      for (int e2 = 0; e2 < 256; ++e2) s += wrow[e2] * kv_w[e2 * 128 + c];
      WkvB[i] = f2bf(s);
    } else if (idx < 196608) {
      int i = idx - 131072;
      int c = i >> 8, e2 = i & 255;
      float s = 0.f;
      for (int e = 0; e < 256; ++e)
        s += fuse_w[c * 256 + e] * out_proj_w[e * 256 + e2];
      M2B[i] = f2bf(s);
    } else if (idx < 196864) {
      int c = idx - 196608;
      float fbv = 0.f;
      for (int e = 0; e < 256; ++e) fbv += fuse_w[c * 256 + e] * out_proj_b[e];
      float inv = gamma[c] * rsqrtf(var[c] + 1e-5f);
      bnpk[c] = make_float2(inv, (fbv - mean[c]) * inv + beta[c]);
      qbias[c] = in_proj_b[c] * QSCALE2;
    }
    return;
  }
  // ---- xpose part ----
  __shared__ u16 tile[64 * 65];
  int i0 = blockIdx.x - 769;
  int b = i0 / 96, rem = i0 % 96;
  int by = rem >> 4, sb = (rem & 15) * 64;
  const float* X;
  u16* XT;
  int C, cb;
  if (by < 4) {
    X = tgt + (size_t)b * 256 * 1024;
    XT = tgtT + (size_t)b * 1024 * 256;
    C = 256;
    cb = by * 64;
  } else {
    X = src + (size_t)b * 128 * 1024;
    XT = srcT + (size_t)b * 1024 * 128;
    C = 128;
    cb = (by - 4) * 64;
  }
  int t = threadIdx.x;
  for (int i = t; i < 4096; i += 256) {
    int c = i >> 6, s = i & 63;
    tile[c * 65 + s] = f2bf(X[(size_t)(cb + c) * 1024 + sb + s]);
  }
  __syncthreads();
  for (int i = t; i < 4096; i += 256) {
    int s = i >> 6, c = i & 63;
    XT[(size_t)(sb + s) * C + cb + c] = tile[c * 65 + s];
  }
}

// ---------------------------------------------------------------------------
// QKV projection, bf16 MFMA, global_load_lds staging (R7 single-buffered —
// measured best; dbuf was neutral-to-negative per R9).
// grid (8, 12, 8): my<4 -> Q (WqB, K=256, tgtT); else KV (WkvB, K=128, srcT).
// Tile 64m x 128n; wave = 64m x 32n (acc 4x2). LDS 12KB.
// ---------------------------------------------------------------------------
__global__ __launch_bounds__(256, 4) void qkv_gemm(
    const u16* __restrict__ tgtT, const u16* __restrict__ srcT,
    const u16* __restrict__ WqB, const u16* __restrict__ WkvB,
    const float* __restrict__ qbias, const float* __restrict__ bkv,
    u16* __restrict__ QB, u16* __restrict__ KB, u16* __restrict__ VB) {
  __shared__ __align__(16) u16 Wl[64 * 32];   // 4KB
  __shared__ __align__(16) u16 Xl[128 * 32];  // 8KB
  int b = blockIdx.z, my = blockIdx.y, n0 = blockIdx.x * 128;
  bool isQ = my < 4;
  int m0 = isQ ? my * 64 : (my - 4) * 64;
  int Kd = isQ ? 256 : 128;
  const u16* Wp = isQ ? WqB : WkvB;
  const u16* Xp = isQ ? tgtT + (size_t)b * 1024 * 256
                      : srcT + (size_t)b * 1024 * 128;
  int t = threadIdx.x, wave = t >> 6, lane = t & 63;
  int lq = lane & 15, quad = lane >> 4;
  int srow = t >> 2, sseg = t & 3;
  f32x4 acc[4][2];
#pragma unroll
  for (int mt = 0; mt < 4; ++mt)
#pragma unroll
    for (int nt = 0; nt < 2; ++nt) acc[mt][nt] = (f32x4){0.f, 0.f, 0.f, 0.f};

  for (int k0 = 0; k0 < Kd; k0 += 32) {
    __syncthreads();
    gl2lds16(&Wp[(size_t)(m0 + srow) * Kd + k0 + sseg * 8], &Wl[wave * 512]);
    gl2lds16(&Xp[(size_t)(n0 + srow) * Kd + k0 + sseg * 8], &Xl[wave * 512]);
    gl2lds16(&Xp[(size_t)(n0 + 64 + srow) * Kd + k0 + sseg * 8],
             &Xl[2048 + wave * 512]);
    __syncthreads();
    short8 af[4], bf[2];
#pragma unroll
    for (int mt = 0; mt < 4; ++mt)
      af[mt] = *(const short8*)&Wl[(mt * 16 + lq) * 32 + quad * 8];
#pragma unroll
    for (int nt = 0; nt < 2; ++nt)
      bf[nt] = *(const short8*)&Xl[(wave * 32 + nt * 16 + lq) * 32 + quad * 8];
#pragma unroll
    for (int mt = 0; mt < 4; ++mt)
#pragma unroll
      for (int nt = 0; nt < 2; ++nt)
        acc[mt][nt] = __builtin_amdgcn_mfma_f32_16x16x32_bf16(af[mt], bf[nt],
                                                              acc[mt][nt], 0, 0, 0);
  }
  if (isQ) {
#pragma unroll
    for (int mt = 0; mt < 4; ++mt) {
      int e = m0 + mt * 16 + quad * 4;
      f32x4 bi = *(const f32x4*)&qbias[e];
#pragma unroll
      for (int nt = 0; nt < 2; ++nt) {
        int n = n0 + wave * 32 + nt * 16 + lq;
        u16x4 pk;
#pragma unroll
        for (int r = 0; r < 4; ++r) pk[r] = f2bf(acc[mt][nt][r] + bi[r]);
        *(u16x4*)&QB[((size_t)b * 1024 + n) * 256 + e] = pk;
      }
    }
  } else {
#pragma unroll
    for (int mt = 0; mt < 4; ++mt) {
      int m = m0 + mt * 16 + quad * 4;
      f32x4 bi = *(const f32x4*)&bkv[m];
#pragma unroll
      for (int nt = 0; nt < 2; ++nt) {
        int n = n0 + wave * 32 + nt * 16 + lq;
        if (m < 256) {
          int hh = m >> 5, d = m & 31;
          u16x4 pk;
#pragma unroll
          for (int r = 0; r < 4; ++r) pk[r] = f2bf(acc[mt][nt][r] + bi[r]);
          *(u16x4*)&KB[((size_t)(b * 8 + hh) * 1024 + n) * 32 + d] = pk;
        } else {
          int e = m - 256;
#pragma unroll
          for (int r = 0; r < 4; ++r)
            VB[((size_t)b * 256 + e + r) * 1024 + n] = f2bf(acc[mt][nt][r] + bi[r]);
        }
      }
    }
  }
}

// ---------------------------------------------------------------------------
// Attention pass A (register-P, transposed scores), R7 single-buffered K/V
// global_load_lds staging. grid (16,8,8)=1024 blocks, 64q, 4 waves x 16q.
// ---------------------------------------------------------------------------
__global__ __launch_bounds__(256, 4) void attn_passA(
    const u16* __restrict__ QB, const u16* __restrict__ KB,
    const u16* __restrict__ VB, u16* __restrict__ ctxB,
    float* __restrict__ linv_ws) {
  __shared__ __align__(16) u16 Klds[128 * 32];  // 8KB, linear rows
  __shared__ __align__(16) u16 Vlds[8 * 544];   // 8.5KB
  int b = blockIdx.z, h = blockIdx.y, q0 = blockIdx.x * 64;
  int t = threadIdx.x, wave = t >> 6, lane = t & 63;
  int lq = lane & 15, quad = lane >> 4;
  int srow = t >> 2, sseg = t & 3;

  const u16* Qb = QB + (size_t)b * 1024 * 256 + h * 32;
  const u16* Kb = KB + (size_t)(b * 8 + h) * 1024 * 32;
  const u16* Vb = VB + (size_t)(b * 256 + h * 32) * 1024;

  int myq = q0 + wave * 16 + lq;
  short8 qf = *(const short8*)(Qb + (size_t)myq * 256 + quad * 8);

  const f32x4 zf = (f32x4){0.f, 0.f, 0.f, 0.f};
  f32x4 O0 = zf, O1 = zf;
  float lsum = 0.f;
  int keyA = ((lq >> 2) << 3) | (lq & 3);
  int vg0 = lane >> 4, vpart = (lane & 15) * 8;

  for (int c0 = 0; c0 < 1024; c0 += 128) {
    __syncthreads();
    gl2lds16(Kb + (size_t)(c0 + srow) * 32 + sseg * 8, &Klds[wave * 512]);
    gl2lds16(Kb + (size_t)(c0 + 64 + srow) * 32 + sseg * 8, &Klds[2048 + wave * 512]);
#pragma unroll
    for (int c = 0; c < 2; ++c) {
      int g = c * 4 + wave;
      gl2lds16(Vb + (size_t)(g * 4 + vg0) * 1024 + c0 + vpart, &Vlds[g * 544]);
    }
    __syncthreads();
#pragma unroll
    for (int pair = 0; pair < 4; ++pair) {
      short8 kf0 = *(const short8*)&Klds[(pair * 32 + keyA) * 32 + quad * 8];
      short8 kf1 = *(const short8*)&Klds[(pair * 32 + keyA + 4) * 32 + quad * 8];
      f32x4 s0 = __builtin_amdgcn_mfma_f32_16x16x32_bf16(kf0, qf, zf, 0, 0, 0);
      f32x4 s1 = __builtin_amdgcn_mfma_f32_16x16x32_bf16(kf1, qf, zf, 0, 0, 0);
      f32x4 e0, e1;
#pragma unroll
      for (int r = 0; r < 4; ++r) {
        e0[r] = exp2f(s0[r]);
        e1[r] = exp2f(s1[r]);
      }
      lsum += (e0[0] + e0[1]) + (e0[2] + e0[3]) +
              (e1[0] + e1[1]) + (e1[2] + e1[3]);
      i32x4 pi;
      pi[0] = (int)pk_trunc(e0[0], e0[1]);
      pi[1] = (int)pk_trunc(e0[2], e0[3]);
      pi[2] = (int)pk_trunc(e1[0], e1[1]);
      pi[3] = (int)pk_trunc(e1[2], e1[3]);
      short8 pf = *(short8*)&pi;
      short8 vf0 = *(const short8*)&Vlds[((lq >> 2) * 544) + (lq & 3) * 128 +
                                         pair * 32 + quad * 8];
      short8 vf1 = *(const short8*)&Vlds[((4 + (lq >> 2)) * 544) + (lq & 3) * 128 +
                                         pair * 32 + quad * 8];
      O0 = __builtin_amdgcn_mfma_f32_16x16x32_bf16(vf0, pf, O0, 0, 0, 0);
      O1 = __builtin_amdgcn_mfma_f32_16x16x32_bf16(vf1, pf, O1, 0, 0, 0);
    }
  }

  lsum += __shfl_xor(lsum, 16);
  lsum += __shfl_xor(lsum, 32);
  float linv = 1.f / lsum;

  u16x4 pk0, pk1;
#pragma unroll
  for (int r = 0; r < 4; ++r) {
    pk0[r] = f2bf(O0[r] * linv);
    pk1[r] = f2bf(O1[r] * linv);
  }
  u16* crow = ctxB + ((size_t)b * 1024 + myq) * 256 + h * 32 + quad * 4;
  *(u16x4*)crow = pk0;
  *(u16x4*)(crow + 16) = pk1;
  if (quad == 0) linv_ws[(size_t)(b * 8 + h) * 1024 + myq] = linv;
}

// ---------------------------------------------------------------------------
// FAT kernel: colsum (even blocks) + fused out-GEMM (odd blocks), one
// dispatch so the two independent stages co-schedule. 1024 blocks -> 4/CU.
// Shared LDS arena: colsum uses 12.3KB (K 8KB + colsum 4KB), fused 8KB.
// ---------------------------------------------------------------------------
__global__ __launch_bounds__(256, 4) void colsum_fused(
    const u16* __restrict__ QB, const u16* __restrict__ KB,
    const float* __restrict__ linv_ws, float* __restrict__ attn_out,
    const u16* __restrict__ M2B, const u16* __restrict__ ctxB,
    const float* __restrict__ tgt, const float2* __restrict__ bnpk,
    float* __restrict__ y) {
  __shared__ __align__(16) u16 smem[6144];  // 12.3KB arena
  int t = threadIdx.x, wave = t >> 6, lane = t & 63;
  int lq = lane & 15, quad = lane >> 4;
  int srow = t >> 2, sseg = t & 3;
  const f32x4 zf = (f32x4){0.f, 0.f, 0.f, 0.f};
  int idx = blockIdx.x >> 1;
  int b = idx >> 6;

  if ((blockIdx.x & 1) == 0) {
    // ================= colsum part: 512 blocks, 128q each =================
    u16* Klds = smem;                         // 8KB
    float* colsum = (float*)(smem + 4096);    // 4KB
    int h = (idx >> 3) & 7, q0 = (idx & 7) * 128;

    const u16* Qb = QB + (size_t)b * 1024 * 256 + h * 32;
    const u16* Kb = KB + (size_t)(b * 8 + h) * 1024 * 32;
    const float* lvp = linv_ws + (size_t)(b * 8 + h) * 1024 + q0 + wave * 32;

    short8 qf2[2];
    f32x4 lv[2];
#pragma unroll
    for (int mt = 0; mt < 2; ++mt) {
      qf2[mt] = *(const short8*)(Qb + (size_t)(q0 + wave * 32 + mt * 16 + lq) * 256 + quad * 8);
      lv[mt] = *(const f32x4*)&lvp[mt * 16 + quad * 4];
    }
    for (int i = t; i < 1024; i += 256) colsum[i] = 0.f;

    for (int c0 = 0; c0 < 1024; c0 += 128) {
      __syncthreads();
      gl2lds16(Kb + (size_t)(c0 + srow) * 32 + sseg * 8, &Klds[wave * 512]);
      gl2lds16(Kb + (size_t)(c0 + 64 + srow) * 32 + sseg * 8,
               &Klds[2048 + wave * 512]);
      __syncthreads();
#pragma unroll
      for (int nt = 0; nt < 8; ++nt) {
        short8 kf = *(const short8*)&Klds[(nt * 16 + lq) * 32 + quad * 8];
        float cs = 0.f;
#pragma unroll
        for (int mt = 0; mt < 2; ++mt) {
          f32x4 s = __builtin_amdgcn_mfma_f32_16x16x32_bf16(qf2[mt], kf, zf, 0, 0, 0);
          cs += exp2f(s[0]) * lv[mt][0] + exp2f(s[1]) * lv[mt][1] +
                exp2f(s[2]) * lv[mt][2] + exp2f(s[3]) * lv[mt][3];
        }
        cs += __shfl_xor(cs, 16);
        cs += __shfl_xor(cs, 32);
        if (quad == 0) atomicAdd(&colsum[c0 + nt * 16 + lq], cs);
      }
    }
    __syncthreads();
    for (int i = t; i < 1024; i += 256)
      atomicAdd(&attn_out[b * 1024 + i], colsum[i] * (1.f / 8192.f));
  } else {
    // ================= fused part: 512 blocks, 64c x 64s =================
    u16* Al = smem;         // 4KB
    u16* Bl = smem + 2048;  // 4KB
    int c0 = ((idx >> 4) & 3) * 64, s0 = (idx & 15) * 64;
    f32x4 acc[4];
#pragma unroll
    for (int mt = 0; mt < 4; ++mt) acc[mt] = (f32x4){0.f, 0.f, 0.f, 0.f};

    const u16* Bp = ctxB + ((size_t)b * 1024 + s0) * 256;
    for (int k0 = 0; k0 < 256; k0 += 32) {
      __syncthreads();
      gl2lds16(&M2B[(size_t)(c0 + srow) * 256 + k0 + sseg * 8], &Al[wave * 512]);
      gl2lds16(&Bp[(size_t)srow * 256 + k0 + sseg * 8], &Bl[wave * 512]);
      __syncthreads();
      short8 bf = *(const short8*)&Bl[(wave * 16 + lq) * 32 + quad * 8];
      short8 af[4];
#pragma unroll
      for (int mt = 0; mt < 4; ++mt)
        af[mt] = *(const short8*)&Al[(mt * 16 + lq) * 32 + quad * 8];
#pragma unroll
      for (int mt = 0; mt < 4; ++mt)
        acc[mt] = __builtin_amdgcn_mfma_f32_16x16x32_bf16(af[mt], bf, acc[mt], 0, 0, 0);
    }
    int s = s0 + wave * 16 + lq;
#pragma unroll
    for (int mt = 0; mt < 4; ++mt) {
#pragma unroll
      for (int r = 0; r < 4; ++r) {
        int c = c0 + mt * 16 + quad * 4 + r;
        float2 p = bnpk[c];
        float bn = acc[mt][r] * p.x + p.y;
        float sig = 1.f / (1.f + __expf(-bn));
        size_t oidx = ((size_t)b * 256 + c) * 1024 + s;
        y[oidx] = tgt[oidx] + bn * sig;
      }
    }
  }
}

// ---------------------------------------------------------------------------
extern "C" void kernel_launch(void* const* d_in, const int* in_sizes, int n_in,
                              void* d_out, int out_size, void* d_ws, size_t ws_size,
                              hipStream_t stream) {
  const float* tgt = (const float*)d_in[0];
  const float* src = (const float*)d_in[1];
  const float* kv_w = (const float*)d_in[2];
  const float* in_proj_w = (const float*)d_in[3];
  const float* in_proj_b = (const float*)d_in[4];
  const float* out_proj_w = (const float*)d_in[5];
  const float* out_proj_b = (const float*)d_in[6];
  const float* fuse_w = (const float*)d_in[7];
  const float* bn_gamma = (const float*)d_in[8];
  const float* bn_beta = (const float*)d_in[9];
  const float* bn_mean = (const float*)d_in[10];
  const float* bn_var = (const float*)d_in[11];

  char* W = (char*)d_ws;
  u16* WqB = (u16*)W;                      // 128KB
  u16* WkvB = (u16*)(W + 131072);          // 128KB
  u16* M2B = (u16*)(W + 262144);           // 128KB
  float* qbias = (float*)(W + 393216);     // 1KB
  float2* bnpk = (float2*)(W + 394240);    // 2KB
  u16* tgtT = (u16*)(W + 397312);          // 4MB (B,S,256) bf16
  u16* srcT = tgtT + 2097152;              // 2MB (B,S,128) bf16
  u16* QB = srcT + 1048576;                // 4MB (B,S,E)
  u16* KB = QB + 2097152;                  // 4MB (B,nH,S,hd)
  u16* VB = KB + 2097152;                  // 4MB (B,E,S)
  u16* ctxB = VB + 2097152;                // 4MB (B,S,E)
  float* linv_ws = (float*)(ctxB + 2097152);  // 256KB (B,nH,S)

  float* y = (float*)d_out;
  float* attn_out = y + 2097152;

  prep_xpose<<<1569, 256, 0, stream>>>(in_proj_w, in_proj_b, kv_w, fuse_w,
                                       out_proj_w, out_proj_b, bn_gamma, bn_beta,
                                       bn_mean, bn_var, tgt, src,
                                       WqB, WkvB, M2B, qbias, bnpk, tgtT, srcT,
                                       attn_out);
  qkv_gemm<<<dim3(8, 12, 8), 256, 0, stream>>>(tgtT, srcT, WqB, WkvB, qbias,
                                               in_proj_b + 256, QB, KB, VB);
  attn_passA<<<dim3(16, 8, 8), 256, 0, stream>>>(QB, KB, VB, ctxB, linv_ws);
  colsum_fused<<<1024, 256, 0, stream>>>(QB, KB, linv_ws, attn_out,
                                         M2B, ctxB, tgt, bnpk, y);
}

// Round 11
// 158.224 us; speedup vs baseline: 1.3053x; 1.0866x over previous
//
#include <hip/hip_runtime.h>
#include <hip/hip_bf16.h>

// B=8, Ct=256, Cs=128, H=W=32, S=1024, E=256, nH=8, hd=32
typedef unsigned short u16;
typedef unsigned int u32;
typedef __attribute__((ext_vector_type(8))) short short8;
typedef __attribute__((ext_vector_type(4))) float f32x4;
typedef __attribute__((ext_vector_type(4))) unsigned short u16x4;
typedef __attribute__((ext_vector_type(4))) int i32x4;

static __device__ __forceinline__ u16 f2bf(float x) {
  __hip_bfloat16 b = __float2bfloat16(x);
  return *reinterpret_cast<u16*>(&b);
}
static __device__ __forceinline__ u32 fbits(float x) {
  union { float f; u32 u; } v; v.f = x; return v.u;
}
// pack two f32 -> two truncated bf16 in one dword
static __device__ __forceinline__ u32 pk_trunc(float lo, float hi) {
  return __builtin_amdgcn_perm(fbits(hi), fbits(lo), 0x07060302u);
}
// async global->LDS, 16B per lane; dest = lds base (wave-uniform) + lane*16
static __device__ __forceinline__ void gl2lds16(const u16* g, u16* l) {
  __builtin_amdgcn_global_load_lds(
      (const __attribute__((address_space(1))) void*)g,
      (__attribute__((address_space(3))) void*)l, 16, 0, 0);
}

// 1/sqrt(32) * log2(e)  (exp2-based softmax)
#define QSCALE2 (0.17677669529663687f * 1.4426950408889634f)

// ---------------------------------------------------------------------------
// Merged prep + transpose-cast + attn_out zero.
// blocks [0,769): prep weights; [769,1537): xpose; [1537,1569): zero attn_out.
// ---------------------------------------------------------------------------
__global__ __launch_bounds__(256) void prep_xpose(
    const float* __restrict__ in_proj_w, const float* __restrict__ in_proj_b,
    const float* __restrict__ kv_w, const float* __restrict__ fuse_w,
    const float* __restrict__ out_proj_w, const float* __restrict__ out_proj_b,
    const float* __restrict__ gamma, const float* __restrict__ beta,
    const float* __restrict__ mean, const float* __restrict__ var,
    const float* __restrict__ tgt, const float* __restrict__ src,
    u16* __restrict__ WqB, u16* __restrict__ WkvB, u16* __restrict__ M2B,
    float* __restrict__ qbias, float2* __restrict__ bnpk,
    u16* __restrict__ tgtT, u16* __restrict__ srcT,
    float* __restrict__ attn_out) {
  if (blockIdx.x >= 1537) {
    int i = (blockIdx.x - 1537) * 256 + threadIdx.x;
    attn_out[i] = 0.f;
    return;
  }
  if (blockIdx.x < 769) {
    int idx = blockIdx.x * 256 + threadIdx.x;
    if (idx < 65536) {
      WqB[idx] = f2bf(in_proj_w[idx] * QSCALE2);
    } else if (idx < 131072) {
      int i = idx - 65536;
      int m = i >> 7, c = i & 127;
      const float* wrow = in_proj_w + (size_t)(256 + m) * 256;
      float s = 0.f;
      for (int e2 = 0; e2 < 256; ++e2) s += wrow[e2] * kv_w[e2 * 128 + c];
      WkvB[i] = f2bf(s);
    } else if (idx < 196608) {
      int i = idx - 131072;
      int c = i >> 8, e2 = i & 255;
      float s = 0.f;
      for (int e = 0; e < 256; ++e)
        s += fuse_w[c * 256 + e] * out_proj_w[e * 256 + e2];
      M2B[i] = f2bf(s);
    } else if (idx < 196864) {
      int c = idx - 196608;
      float fbv = 0.f;
      for (int e = 0; e < 256; ++e) fbv += fuse_w[c * 256 + e] * out_proj_b[e];
      float inv = gamma[c] * rsqrtf(var[c] + 1e-5f);
      bnpk[c] = make_float2(inv, (fbv - mean[c]) * inv + beta[c]);
      qbias[c] = in_proj_b[c] * QSCALE2;
    }
    return;
  }
  // ---- xpose part ----
  __shared__ u16 tile[64 * 65];
  int i0 = blockIdx.x - 769;
  int b = i0 / 96, rem = i0 % 96;
  int by = rem >> 4, sb = (rem & 15) * 64;
  const float* X;
  u16* XT;
  int C, cb;
  if (by < 4) {
    X = tgt + (size_t)b * 256 * 1024;
    XT = tgtT + (size_t)b * 1024 * 256;
    C = 256;
    cb = by * 64;
  } else {
    X = src + (size_t)b * 128 * 1024;
    XT = srcT + (size_t)b * 1024 * 128;
    C = 128;
    cb = (by - 4) * 64;
  }
  int t = threadIdx.x;
  for (int i = t; i < 4096; i += 256) {
    int c = i >> 6, s = i & 63;
    tile[c * 65 + s] = f2bf(X[(size_t)(cb + c) * 1024 + sb + s]);
  }
  __syncthreads();
  for (int i = t; i < 4096; i += 256) {
    int s = i >> 6, c = i & 63;
    XT[(size_t)(sb + s) * C + cb + c] = tile[c * 65 + s];
  }
}

// ---------------------------------------------------------------------------
// QKV projection (R7-exact, measured best): bf16 MFMA, single-buffered
// global_load_lds staging. grid (8,12,8). Tile 64m x 128n. LDS 12KB.
// ---------------------------------------------------------------------------
__global__ __launch_bounds__(256, 4) void qkv_gemm(
    const u16* __restrict__ tgtT, const u16* __restrict__ srcT,
    const u16* __restrict__ WqB, const u16* __restrict__ WkvB,
    const float* __restrict__ qbias, const float* __restrict__ bkv,
    u16* __restrict__ QB, u16* __restrict__ KB, u16* __restrict__ VB) {
  __shared__ __align__(16) u16 Wl[64 * 32];   // 4KB
  __shared__ __align__(16) u16 Xl[128 * 32];  // 8KB
  int b = blockIdx.z, my = blockIdx.y, n0 = blockIdx.x * 128;
  bool isQ = my < 4;
  int m0 = isQ ? my * 64 : (my - 4) * 64;
  int Kd = isQ ? 256 : 128;
  const u16* Wp = isQ ? WqB : WkvB;
  const u16* Xp = isQ ? tgtT + (size_t)b * 1024 * 256
                      : srcT + (size_t)b * 1024 * 128;
  int t = threadIdx.x, wave = t >> 6, lane = t & 63;
  int lq = lane & 15, quad = lane >> 4;
  int srow = t >> 2, sseg = t & 3;
  f32x4 acc[4][2];
#pragma unroll
  for (int mt = 0; mt < 4; ++mt)
#pragma unroll
    for (int nt = 0; nt < 2; ++nt) acc[mt][nt] = (f32x4){0.f, 0.f, 0.f, 0.f};

  for (int k0 = 0; k0 < Kd; k0 += 32) {
    __syncthreads();
    gl2lds16(&Wp[(size_t)(m0 + srow) * Kd + k0 + sseg * 8], &Wl[wave * 512]);
    gl2lds16(&Xp[(size_t)(n0 + srow) * Kd + k0 + sseg * 8], &Xl[wave * 512]);
    gl2lds16(&Xp[(size_t)(n0 + 64 + srow) * Kd + k0 + sseg * 8],
             &Xl[2048 + wave * 512]);
    __syncthreads();
    short8 af[4], bf[2];
#pragma unroll
    for (int mt = 0; mt < 4; ++mt)
      af[mt] = *(const short8*)&Wl[(mt * 16 + lq) * 32 + quad * 8];
#pragma unroll
    for (int nt = 0; nt < 2; ++nt)
      bf[nt] = *(const short8*)&Xl[(wave * 32 + nt * 16 + lq) * 32 + quad * 8];
#pragma unroll
    for (int mt = 0; mt < 4; ++mt)
#pragma unroll
      for (int nt = 0; nt < 2; ++nt)
        acc[mt][nt] = __builtin_amdgcn_mfma_f32_16x16x32_bf16(af[mt], bf[nt],
                                                              acc[mt][nt], 0, 0, 0);
  }
  if (isQ) {
#pragma unroll
    for (int mt = 0; mt < 4; ++mt) {
      int e = m0 + mt * 16 + quad * 4;
      f32x4 bi = *(const f32x4*)&qbias[e];
#pragma unroll
      for (int nt = 0; nt < 2; ++nt) {
        int n = n0 + wave * 32 + nt * 16 + lq;
        u16x4 pk;
#pragma unroll
        for (int r = 0; r < 4; ++r) pk[r] = f2bf(acc[mt][nt][r] + bi[r]);
        *(u16x4*)&QB[((size_t)b * 1024 + n) * 256 + e] = pk;
      }
    }
  } else {
#pragma unroll
    for (int mt = 0; mt < 4; ++mt) {
      int m = m0 + mt * 16 + quad * 4;
      f32x4 bi = *(const f32x4*)&bkv[m];
#pragma unroll
      for (int nt = 0; nt < 2; ++nt) {
        int n = n0 + wave * 32 + nt * 16 + lq;
        if (m < 256) {
          int hh = m >> 5, d = m & 31;
          u16x4 pk;
#pragma unroll
          for (int r = 0; r < 4; ++r) pk[r] = f2bf(acc[mt][nt][r] + bi[r]);
          *(u16x4*)&KB[((size_t)(b * 8 + hh) * 1024 + n) * 32 + d] = pk;
        } else {
          int e = m - 256;
#pragma unroll
          for (int r = 0; r < 4; ++r)
            VB[((size_t)b * 256 + e + r) * 1024 + n] = f2bf(acc[mt][nt][r] + bi[r]);
        }
      }
    }
  }
}

// ---------------------------------------------------------------------------
// Attention pass A (R7 math: register-P transposed scores) with:
//  - 256-key chunks (4 barrier pairs instead of 8), LDS 33KB -> 4 blocks/CU
//  - XCD swizzle: 1D grid, idx = qt*64 + pair; q-tiles of one (b,h) land on
//    the same XCD (stride 64 = 0 mod 8) so K/V stay in one L2.
// ---------------------------------------------------------------------------
__global__ __launch_bounds__(256, 4) void attn_passA(
    const u16* __restrict__ QB, const u16* __restrict__ KB,
    const u16* __restrict__ VB, u16* __restrict__ ctxB,
    float* __restrict__ linv_ws) {
  __shared__ __align__(16) u16 Klds[256 * 32];  // 16KB, linear rows
  __shared__ __align__(16) u16 Vlds[8 * 1056];  // 16.9KB: group g = 4 d-rows x 256 keys
  int bidx = blockIdx.x;
  int pair = bidx & 63, q0 = (bidx >> 6) * 64;
  int b = pair >> 3, h = pair & 7;
  int t = threadIdx.x, wave = t >> 6, lane = t & 63;
  int lq = lane & 15, quad = lane >> 4;
  int srow = t >> 2, sseg = t & 3;

  const u16* Qb = QB + (size_t)b * 1024 * 256 + h * 32;
  const u16* Kb = KB + (size_t)pair * 1024 * 32;
  const u16* Vb = VB + (size_t)(b * 256 + h * 32) * 1024;

  int myq = q0 + wave * 16 + lq;
  short8 qf = *(const short8*)(Qb + (size_t)myq * 256 + quad * 8);

  const f32x4 zf = (f32x4){0.f, 0.f, 0.f, 0.f};
  f32x4 O0 = zf, O1 = zf;
  float lsum = 0.f;
  int keyA = ((lq >> 2) << 3) | (lq & 3);

  for (int c0 = 0; c0 < 1024; c0 += 256) {
    __syncthreads();
    // K: 256 rows x 64B, 4 calls/thread
#pragma unroll
    for (int i = 0; i < 4; ++i)
      gl2lds16(Kb + (size_t)(c0 + i * 64 + srow) * 32 + sseg * 8,
               &Klds[i * 2048 + wave * 512]);
    // V: 8 groups of 4 d-rows x 256 keys; call j covers rows g*4+j*2+(lane>>5)
#pragma unroll
    for (int i = 0; i < 2; ++i) {
      int g = wave * 2 + i;
#pragma unroll
      for (int j = 0; j < 2; ++j) {
        int d = g * 4 + j * 2 + (lane >> 5);
        gl2lds16(Vb + (size_t)d * 1024 + c0 + (lane & 31) * 8,
                 &Vlds[g * 1056 + j * 512]);
      }
    }
    __syncthreads();
#pragma unroll
    for (int pr = 0; pr < 8; ++pr) {
      short8 kf0 = *(const short8*)&Klds[(pr * 32 + keyA) * 32 + quad * 8];
      short8 kf1 = *(const short8*)&Klds[(pr * 32 + keyA + 4) * 32 + quad * 8];
      f32x4 s0 = __builtin_amdgcn_mfma_f32_16x16x32_bf16(kf0, qf, zf, 0, 0, 0);
      f32x4 s1 = __builtin_amdgcn_mfma_f32_16x16x32_bf16(kf1, qf, zf, 0, 0, 0);
      f32x4 e0, e1;
#pragma unroll
      for (int r = 0; r < 4; ++r) {
        e0[r] = exp2f(s0[r]);
        e1[r] = exp2f(s1[r]);
      }
      lsum += (e0[0] + e0[1]) + (e0[2] + e0[3]) +
              (e1[0] + e1[1]) + (e1[2] + e1[3]);
      i32x4 pi;
      pi[0] = (int)pk_trunc(e0[0], e0[1]);
      pi[1] = (int)pk_trunc(e0[2], e0[3]);
      pi[2] = (int)pk_trunc(e1[0], e1[1]);
      pi[3] = (int)pk_trunc(e1[2], e1[3]);
      short8 pf = *(short8*)&pi;
      short8 vf0 = *(const short8*)&Vlds[(lq >> 2) * 1056 + (lq & 3) * 256 +
                                         pr * 32 + quad * 8];
      short8 vf1 = *(const short8*)&Vlds[(4 + (lq >> 2)) * 1056 + (lq & 3) * 256 +
                                         pr * 32 + quad * 8];
      O0 = __builtin_amdgcn_mfma_f32_16x16x32_bf16(vf0, pf, O0, 0, 0, 0);
      O1 = __builtin_amdgcn_mfma_f32_16x16x32_bf16(vf1, pf, O1, 0, 0, 0);
    }
  }

  lsum += __shfl_xor(lsum, 16);
  lsum += __shfl_xor(lsum, 32);
  float linv = 1.f / lsum;

  u16x4 pk0, pk1;
#pragma unroll
  for (int r = 0; r < 4; ++r) {
    pk0[r] = f2bf(O0[r] * linv);
    pk1[r] = f2bf(O1[r] * linv);
  }
  u16* crow = ctxB + ((size_t)b * 1024 + myq) * 256 + h * 32 + quad * 4;
  *(u16x4*)crow = pk0;
  *(u16x4*)(crow + 16) = pk1;
  if (quad == 0) linv_ws[(size_t)pair * 1024 + myq] = linv;
}

// ---------------------------------------------------------------------------
// Colsum, key-owning blocks: block = (b,h, 64-key chunk). K staged ONCE
// (1 barrier), K-frags hoisted to registers, 16 query-group iterations
// streaming Q/linv from global, pure-register column accumulation.
// grid 1024 (1D, idx = kchunk*64 + pair for XCD locality). LDS 4KB.
// ---------------------------------------------------------------------------
__global__ __launch_bounds__(256, 4) void colsum_kernel(
    const u16* __restrict__ QB, const u16* __restrict__ KB,
    const float* __restrict__ linv_ws, float* __restrict__ attn_out) {
  __shared__ __align__(16) u16 Klds[64 * 32];  // 4KB
  int bidx = blockIdx.x;
  int pair = bidx & 63, k0 = (bidx >> 6) * 64;
  int b = pair >> 3, h = pair & 7;
  int t = threadIdx.x, wave = t >> 6, lane = t & 63;
  int lq = lane & 15, quad = lane >> 4;
  int srow = t >> 2, sseg = t & 3;

  const u16* Qb = QB + (size_t)b * 1024 * 256 + h * 32;
  const u16* Kb = KB + (size_t)pair * 1024 * 32;
  const float* lvp = linv_ws + (size_t)pair * 1024;

  gl2lds16(Kb + (size_t)(k0 + srow) * 32 + sseg * 8, &Klds[wave * 512]);
  __syncthreads();

  short8 kf[4];
#pragma unroll
  for (int nt = 0; nt < 4; ++nt)
    kf[nt] = *(const short8*)&Klds[(nt * 16 + lq) * 32 + quad * 8];

  const f32x4 zf = (f32x4){0.f, 0.f, 0.f, 0.f};
  float cs[4] = {0.f, 0.f, 0.f, 0.f};
  // wave handles queries q = g*64 + wave*16 + {0..15}, g in [0,16)
  for (int g = 0; g < 16; ++g) {
    int qg = g * 64 + wave * 16;
    short8 qf = *(const short8*)(Qb + (size_t)(qg + lq) * 256 + quad * 8);
    f32x4 lv = *(const f32x4*)&lvp[qg + quad * 4];
#pragma unroll
    for (int nt = 0; nt < 4; ++nt) {
      f32x4 s = __builtin_amdgcn_mfma_f32_16x16x32_bf16(qf, kf[nt], zf, 0, 0, 0);
      cs[nt] += exp2f(s[0]) * lv[0] + exp2f(s[1]) * lv[1] +
                exp2f(s[2]) * lv[2] + exp2f(s[3]) * lv[3];
    }
  }
#pragma unroll
  for (int nt = 0; nt < 4; ++nt) {
    float v = cs[nt];
    v += __shfl_xor(v, 16);
    v += __shfl_xor(v, 32);
    if (quad == 0)
      atomicAdd(&attn_out[b * 1024 + k0 + nt * 16 + lq], v * (1.f / 8192.f));
  }
}

// ---------------------------------------------------------------------------
// Fused out GEMM + BN + SiLU + residual (R7-exact). Tile 64c x 64s,
// grid (16,4,8)=512. LDS 8KB.
// ---------------------------------------------------------------------------
__global__ __launch_bounds__(256, 4) void fused_out(
    const u16* __restrict__ M2B, const u16* __restrict__ ctxB,
    const float* __restrict__ tgt, const float2* __restrict__ bnpk,
    float* __restrict__ y) {
  __shared__ __align__(16) u16 Al[64 * 32];  // 4KB
  __shared__ __align__(16) u16 Bl[64 * 32];  // 4KB
  int b = blockIdx.z, c0 = blockIdx.y * 64, s0 = blockIdx.x * 64;
  int t = threadIdx.x, wave = t >> 6, lane = t & 63;
  int lq = lane & 15, quad = lane >> 4;
  int srow = t >> 2, sseg = t & 3;
  f32x4 acc[4];
#pragma unroll
  for (int mt = 0; mt < 4; ++mt) acc[mt] = (f32x4){0.f, 0.f, 0.f, 0.f};

  for (int k0 = 0; k0 < 256; k0 += 32) {
    __syncthreads();
    gl2lds16(&M2B[(size_t)(c0 + srow) * 256 + k0 + sseg * 8], &Al[wave * 512]);
    gl2lds16(&ctxB[((size_t)b * 1024 + s0 + srow) * 256 + k0 + sseg * 8],
             &Bl[wave * 512]);
    __syncthreads();
    short8 bf = *(const short8*)&Bl[(wave * 16 + lq) * 32 + quad * 8];
    short8 af[4];
#pragma unroll
    for (int mt = 0; mt < 4; ++mt)
      af[mt] = *(const short8*)&Al[(mt * 16 + lq) * 32 + quad * 8];
#pragma unroll
    for (int mt = 0; mt < 4; ++mt)
      acc[mt] = __builtin_amdgcn_mfma_f32_16x16x32_bf16(af[mt], bf, acc[mt], 0, 0, 0);
  }
  int s = s0 + wave * 16 + lq;
#pragma unroll
  for (int mt = 0; mt < 4; ++mt) {
#pragma unroll
    for (int r = 0; r < 4; ++r) {
      int c = c0 + mt * 16 + quad * 4 + r;
      float2 p = bnpk[c];
      float bn = acc[mt][r] * p.x + p.y;
      float sig = 1.f / (1.f + __expf(-bn));
      size_t idx = ((size_t)b * 256 + c) * 1024 + s;
      y[idx] = tgt[idx] + bn * sig;
    }
  }
}

// ---------------------------------------------------------------------------
extern "C" void kernel_launch(void* const* d_in, const int* in_sizes, int n_in,
                              void* d_out, int out_size, void* d_ws, size_t ws_size,
                              hipStream_t stream) {
  const float* tgt = (const float*)d_in[0];
  const float* src = (const float*)d_in[1];
  const float* kv_w = (const float*)d_in[2];
  const float* in_proj_w = (const float*)d_in[3];
  const float* in_proj_b = (const float*)d_in[4];
  const float* out_proj_w = (const float*)d_in[5];
  const float* out_proj_b = (const float*)d_in[6];
  const float* fuse_w = (const float*)d_in[7];
  const float* bn_gamma = (const float*)d_in[8];
  const float* bn_beta = (const float*)d_in[9];
  const float* bn_mean = (const float*)d_in[10];
  const float* bn_var = (const float*)d_in[11];

  char* W = (char*)d_ws;
  u16* WqB = (u16*)W;                      // 128KB
  u16* WkvB = (u16*)(W + 131072);          // 128KB
  u16* M2B = (u16*)(W + 262144);           // 128KB
  float* qbias = (float*)(W + 393216);     // 1KB
  float2* bnpk = (float2*)(W + 394240);    // 2KB
  u16* tgtT = (u16*)(W + 397312);          // 4MB (B,S,256) bf16
  u16* srcT = tgtT + 2097152;              // 2MB (B,S,128) bf16
  u16* QB = srcT + 1048576;                // 4MB (B,S,E)
  u16* KB = QB + 2097152;                  // 4MB (B,nH,S,hd)
  u16* VB = KB + 2097152;                  // 4MB (B,E,S)
  u16* ctxB = VB + 2097152;                // 4MB (B,S,E)
  float* linv_ws = (float*)(ctxB + 2097152);  // 256KB (B,nH,S)

  float* y = (float*)d_out;
  float* attn_out = y + 2097152;

  prep_xpose<<<1569, 256, 0, stream>>>(in_proj_w, in_proj_b, kv_w, fuse_w,
                                       out_proj_w, out_proj_b, bn_gamma, bn_beta,
                                       bn_mean, bn_var, tgt, src,
                                       WqB, WkvB, M2B, qbias, bnpk, tgtT, srcT,
                                       attn_out);
  qkv_gemm<<<dim3(8, 12, 8), 256, 0, stream>>>(tgtT, srcT, WqB, WkvB, qbias,
                                               in_proj_b + 256, QB, KB, VB);
  attn_passA<<<1024, 256, 0, stream>>>(QB, KB, VB, ctxB, linv_ws);
  colsum_kernel<<<1024, 256, 0, stream>>>(QB, KB, linv_ws, attn_out);
  fused_out<<<dim3(16, 4, 8), 256, 0, stream>>>(M2B, ctxB, tgt, bnpk, y);
}

// Round 12
// 157.901 us; speedup vs baseline: 1.3080x; 1.0020x over previous
//
#include <hip/hip_runtime.h>
#include <hip/hip_bf16.h>

// B=8, Ct=256, Cs=128, H=W=32, S=1024, E=256, nH=8, hd=32
typedef unsigned short u16;
typedef unsigned int u32;
typedef __attribute__((ext_vector_type(8))) short short8;
typedef __attribute__((ext_vector_type(4))) float f32x4;
typedef __attribute__((ext_vector_type(4))) unsigned short u16x4;
typedef __attribute__((ext_vector_type(4))) int i32x4;

static __device__ __forceinline__ u16 f2bf(float x) {
  __hip_bfloat16 b = __float2bfloat16(x);
  return *reinterpret_cast<u16*>(&b);
}
static __device__ __forceinline__ u32 fbits(float x) {
  union { float f; u32 u; } v; v.f = x; return v.u;
}
// pack two f32 -> two truncated bf16 in one dword
static __device__ __forceinline__ u32 pk_trunc(float lo, float hi) {
  return __builtin_amdgcn_perm(fbits(hi), fbits(lo), 0x07060302u);
}
// async global->LDS, 16B per lane; dest = lds base (wave-uniform) + lane*16
static __device__ __forceinline__ void gl2lds16(const u16* g, u16* l) {
  __builtin_amdgcn_global_load_lds(
      (const __attribute__((address_space(1))) void*)g,
      (__attribute__((address_space(3))) void*)l, 16, 0, 0);
}

// 1/sqrt(32) * log2(e)  (exp2-based softmax)
#define QSCALE2 (0.17677669529663687f * 1.4426950408889634f)

// ---------------------------------------------------------------------------
// Merged prep + register-transpose-cast + attn_out zero.
// blocks [0,769): prep weights; [769,1537): xpose; [1537,1569): zero attn_out.
// xpose: each thread owns a 4x4 micro-tile -> 4 coalesced float4 loads,
// 16 f2bf, 4 u16x4 stores. No LDS, no barrier.
// ---------------------------------------------------------------------------
__global__ __launch_bounds__(256) void prep_xpose(
    const float* __restrict__ in_proj_w, const float* __restrict__ in_proj_b,
    const float* __restrict__ kv_w, const float* __restrict__ fuse_w,
    const float* __restrict__ out_proj_w, const float* __restrict__ out_proj_b,
    const float* __restrict__ gamma, const float* __restrict__ beta,
    const float* __restrict__ mean, const float* __restrict__ var,
    const float* __restrict__ tgt, const float* __restrict__ src,
    u16* __restrict__ WqB, u16* __restrict__ WkvB, u16* __restrict__ M2B,
    float* __restrict__ qbias, float2* __restrict__ bnpk,
    u16* __restrict__ tgtT, u16* __restrict__ srcT,
    float* __restrict__ attn_out) {
  if (blockIdx.x >= 1537) {
    int i = (blockIdx.x - 1537) * 256 + threadIdx.x;
    attn_out[i] = 0.f;
    return;
  }
  if (blockIdx.x < 769) {
    int idx = blockIdx.x * 256 + threadIdx.x;
    if (idx < 65536) {
      WqB[idx] = f2bf(in_proj_w[idx] * QSCALE2);
    } else if (idx < 131072) {
      int i = idx - 65536;
      int m = i >> 7, c = i & 127;
      const float* wrow = in_proj_w + (size_t)(256 + m) * 256;
      float s = 0.f;
      for (int e2 = 0; e2 < 256; ++e2) s += wrow[e2] * kv_w[e2 * 128 + c];
      WkvB[i] = f2bf(s);
    } else if (idx < 196608) {
      int i = idx - 131072;
      int c = i >> 8, e2 = i & 255;
      float s = 0.f;
      for (int e = 0; e < 256; ++e)
        s += fuse_w[c * 256 + e] * out_proj_w[e * 256 + e2];
      M2B[i] = f2bf(s);
    } else if (idx < 196864) {
      int c = idx - 196608;
      float fbv = 0.f;
      for (int e = 0; e < 256; ++e) fbv += fuse_w[c * 256 + e] * out_proj_b[e];
      float inv = gamma[c] * rsqrtf(var[c] + 1e-5f);
      bnpk[c] = make_float2(inv, (fbv - mean[c]) * inv + beta[c]);
      qbias[c] = in_proj_b[c] * QSCALE2;
    }
    return;
  }
  // ---- xpose part: register 4x4 transpose-cast ----
  int i0 = blockIdx.x - 769;
  int b = i0 / 96, rem = i0 % 96;
  int by = rem >> 4, sb = (rem & 15) * 64;
  const float* X;
  u16* XT;
  int C, cb;
  if (by < 4) {
    X = tgt + (size_t)b * 256 * 1024;
    XT = tgtT + (size_t)b * 1024 * 256;
    C = 256;
    cb = by * 64;
  } else {
    X = src + (size_t)b * 128 * 1024;
    XT = srcT + (size_t)b * 1024 * 128;
    C = 128;
    cb = (by - 4) * 64;
  }
  int t = threadIdx.x;
  int c = cb + (t >> 4) * 4;
  int s = sb + (t & 15) * 4;
  const float* Xp = X + (size_t)c * 1024 + s;
  float4 r0 = *(const float4*)(Xp);
  float4 r1 = *(const float4*)(Xp + 1024);
  float4 r2 = *(const float4*)(Xp + 2048);
  float4 r3 = *(const float4*)(Xp + 3072);
  u16* XTp = XT + (size_t)s * C + c;
  u16x4 o;
  o[0] = f2bf(r0.x); o[1] = f2bf(r1.x); o[2] = f2bf(r2.x); o[3] = f2bf(r3.x);
  *(u16x4*)(XTp) = o;
  o[0] = f2bf(r0.y); o[1] = f2bf(r1.y); o[2] = f2bf(r2.y); o[3] = f2bf(r3.y);
  *(u16x4*)(XTp + C) = o;
  o[0] = f2bf(r0.z); o[1] = f2bf(r1.z); o[2] = f2bf(r2.z); o[3] = f2bf(r3.z);
  *(u16x4*)(XTp + 2 * C) = o;
  o[0] = f2bf(r0.w); o[1] = f2bf(r1.w); o[2] = f2bf(r2.w); o[3] = f2bf(r3.w);
  *(u16x4*)(XTp + 3 * C) = o;
}

// ---------------------------------------------------------------------------
// QKV projection (R7-exact staging, measured best): bf16 MFMA, single-buffered
// global_load_lds. grid (8,12,8). Tile 64m x 128n. LDS 12KB.
// QB now written in (B,nH,S,hd) layout (same as KB) for attention locality.
// ---------------------------------------------------------------------------
__global__ __launch_bounds__(256, 4) void qkv_gemm(
    const u16* __restrict__ tgtT, const u16* __restrict__ srcT,
    const u16* __restrict__ WqB, const u16* __restrict__ WkvB,
    const float* __restrict__ qbias, const float* __restrict__ bkv,
    u16* __restrict__ QB, u16* __restrict__ KB, u16* __restrict__ VB) {
  __shared__ __align__(16) u16 Wl[64 * 32];   // 4KB
  __shared__ __align__(16) u16 Xl[128 * 32];  // 8KB
  int b = blockIdx.z, my = blockIdx.y, n0 = blockIdx.x * 128;
  bool isQ = my < 4;
  int m0 = isQ ? my * 64 : (my - 4) * 64;
  int Kd = isQ ? 256 : 128;
  const u16* Wp = isQ ? WqB : WkvB;
  const u16* Xp = isQ ? tgtT + (size_t)b * 1024 * 256
                      : srcT + (size_t)b * 1024 * 128;
  int t = threadIdx.x, wave = t >> 6, lane = t & 63;
  int lq = lane & 15, quad = lane >> 4;
  int srow = t >> 2, sseg = t & 3;
  f32x4 acc[4][2];
#pragma unroll
  for (int mt = 0; mt < 4; ++mt)
#pragma unroll
    for (int nt = 0; nt < 2; ++nt) acc[mt][nt] = (f32x4){0.f, 0.f, 0.f, 0.f};

  for (int k0 = 0; k0 < Kd; k0 += 32) {
    __syncthreads();
    gl2lds16(&Wp[(size_t)(m0 + srow) * Kd + k0 + sseg * 8], &Wl[wave * 512]);
    gl2lds16(&Xp[(size_t)(n0 + srow) * Kd + k0 + sseg * 8], &Xl[wave * 512]);
    gl2lds16(&Xp[(size_t)(n0 + 64 + srow) * Kd + k0 + sseg * 8],
             &Xl[2048 + wave * 512]);
    __syncthreads();
    short8 af[4], bf[2];
#pragma unroll
    for (int mt = 0; mt < 4; ++mt)
      af[mt] = *(const short8*)&Wl[(mt * 16 + lq) * 32 + quad * 8];
#pragma unroll
    for (int nt = 0; nt < 2; ++nt)
      bf[nt] = *(const short8*)&Xl[(wave * 32 + nt * 16 + lq) * 32 + quad * 8];
#pragma unroll
    for (int mt = 0; mt < 4; ++mt)
#pragma unroll
      for (int nt = 0; nt < 2; ++nt)
        acc[mt][nt] = __builtin_amdgcn_mfma_f32_16x16x32_bf16(af[mt], bf[nt],
                                                              acc[mt][nt], 0, 0, 0);
  }
  if (isQ) {
#pragma unroll
    for (int mt = 0; mt < 4; ++mt) {
      int e = m0 + mt * 16 + quad * 4;
      f32x4 bi = *(const f32x4*)&qbias[e];
      int hh = e >> 5, d0 = e & 31;
#pragma unroll
      for (int nt = 0; nt < 2; ++nt) {
        int n = n0 + wave * 32 + nt * 16 + lq;
        u16x4 pk;
#pragma unroll
        for (int r = 0; r < 4; ++r) pk[r] = f2bf(acc[mt][nt][r] + bi[r]);
        *(u16x4*)&QB[((size_t)(b * 8 + hh) * 1024 + n) * 32 + d0] = pk;
      }
    }
  } else {
#pragma unroll
    for (int mt = 0; mt < 4; ++mt) {
      int m = m0 + mt * 16 + quad * 4;
      f32x4 bi = *(const f32x4*)&bkv[m];
#pragma unroll
      for (int nt = 0; nt < 2; ++nt) {
        int n = n0 + wave * 32 + nt * 16 + lq;
        if (m < 256) {
          int hh = m >> 5, d = m & 31;
          u16x4 pk;
#pragma unroll
          for (int r = 0; r < 4; ++r) pk[r] = f2bf(acc[mt][nt][r] + bi[r]);
          *(u16x4*)&KB[((size_t)(b * 8 + hh) * 1024 + n) * 32 + d] = pk;
        } else {
          int e = m - 256;
#pragma unroll
          for (int r = 0; r < 4; ++r)
            VB[((size_t)b * 256 + e + r) * 1024 + n] = f2bf(acc[mt][nt][r] + bi[r]);
        }
      }
    }
  }
}

// ---------------------------------------------------------------------------
// Attention pass A (R11-exact): register-P transposed scores, 256-key chunks,
// XCD swizzle (idx = qt*64 + pair). QB now (B,nH,S,hd).
// ---------------------------------------------------------------------------
__global__ __launch_bounds__(256, 4) void attn_passA(
    const u16* __restrict__ QB, const u16* __restrict__ KB,
    const u16* __restrict__ VB, u16* __restrict__ ctxB,
    float* __restrict__ linv_ws) {
  __shared__ __align__(16) u16 Klds[256 * 32];  // 16KB, linear rows
  __shared__ __align__(16) u16 Vlds[8 * 1056];  // 16.9KB
  int bidx = blockIdx.x;
  int pair = bidx & 63, q0 = (bidx >> 6) * 64;
  int b = pair >> 3, h = pair & 7;
  int t = threadIdx.x, wave = t >> 6, lane = t & 63;
  int lq = lane & 15, quad = lane >> 4;
  int srow = t >> 2, sseg = t & 3;

  const u16* Qb = QB + (size_t)pair * 1024 * 32;
  const u16* Kb = KB + (size_t)pair * 1024 * 32;
  const u16* Vb = VB + (size_t)(b * 256 + h * 32) * 1024;

  int myq = q0 + wave * 16 + lq;
  short8 qf = *(const short8*)(Qb + (size_t)myq * 32 + quad * 8);

  const f32x4 zf = (f32x4){0.f, 0.f, 0.f, 0.f};
  f32x4 O0 = zf, O1 = zf;
  float lsum = 0.f;
  int keyA = ((lq >> 2) << 3) | (lq & 3);

  for (int c0 = 0; c0 < 1024; c0 += 256) {
    __syncthreads();
#pragma unroll
    for (int i = 0; i < 4; ++i)
      gl2lds16(Kb + (size_t)(c0 + i * 64 + srow) * 32 + sseg * 8,
               &Klds[i * 2048 + wave * 512]);
#pragma unroll
    for (int i = 0; i < 2; ++i) {
      int g = wave * 2 + i;
#pragma unroll
      for (int j = 0; j < 2; ++j) {
        int d = g * 4 + j * 2 + (lane >> 5);
        gl2lds16(Vb + (size_t)d * 1024 + c0 + (lane & 31) * 8,
                 &Vlds[g * 1056 + j * 512]);
      }
    }
    __syncthreads();
#pragma unroll
    for (int pr = 0; pr < 8; ++pr) {
      short8 kf0 = *(const short8*)&Klds[(pr * 32 + keyA) * 32 + quad * 8];
      short8 kf1 = *(const short8*)&Klds[(pr * 32 + keyA + 4) * 32 + quad * 8];
      f32x4 s0 = __builtin_amdgcn_mfma_f32_16x16x32_bf16(kf0, qf, zf, 0, 0, 0);
      f32x4 s1 = __builtin_amdgcn_mfma_f32_16x16x32_bf16(kf1, qf, zf, 0, 0, 0);
      f32x4 e0, e1;
#pragma unroll
      for (int r = 0; r < 4; ++r) {
        e0[r] = exp2f(s0[r]);
        e1[r] = exp2f(s1[r]);
      }
      lsum += (e0[0] + e0[1]) + (e0[2] + e0[3]) +
              (e1[0] + e1[1]) + (e1[2] + e1[3]);
      i32x4 pi;
      pi[0] = (int)pk_trunc(e0[0], e0[1]);
      pi[1] = (int)pk_trunc(e0[2], e0[3]);
      pi[2] = (int)pk_trunc(e1[0], e1[1]);
      pi[3] = (int)pk_trunc(e1[2], e1[3]);
      short8 pf = *(short8*)&pi;
      short8 vf0 = *(const short8*)&Vlds[(lq >> 2) * 1056 + (lq & 3) * 256 +
                                         pr * 32 + quad * 8];
      short8 vf1 = *(const short8*)&Vlds[(4 + (lq >> 2)) * 1056 + (lq & 3) * 256 +
                                         pr * 32 + quad * 8];
      O0 = __builtin_amdgcn_mfma_f32_16x16x32_bf16(vf0, pf, O0, 0, 0, 0);
      O1 = __builtin_amdgcn_mfma_f32_16x16x32_bf16(vf1, pf, O1, 0, 0, 0);
    }
  }

  lsum += __shfl_xor(lsum, 16);
  lsum += __shfl_xor(lsum, 32);
  float linv = 1.f / lsum;

  u16x4 pk0, pk1;
#pragma unroll
  for (int r = 0; r < 4; ++r) {
    pk0[r] = f2bf(O0[r] * linv);
    pk1[r] = f2bf(O1[r] * linv);
  }
  u16* crow = ctxB + ((size_t)b * 1024 + myq) * 256 + h * 32 + quad * 4;
  *(u16x4*)crow = pk0;
  *(u16x4*)(crow + 16) = pk1;
  if (quad == 0) linv_ws[(size_t)pair * 1024 + myq] = linv;
}

// ---------------------------------------------------------------------------
// Colsum, key-owning blocks (R11-exact): K staged once, register K-frags,
// 16 query-group iterations streaming Q/linv from global. QB now (B,nH,S,hd).
// grid 1024 (idx = kchunk*64 + pair). LDS 4KB.
// ---------------------------------------------------------------------------
__global__ __launch_bounds__(256, 4) void colsum_kernel(
    const u16* __restrict__ QB, const u16* __restrict__ KB,
    const float* __restrict__ linv_ws, float* __restrict__ attn_out) {
  __shared__ __align__(16) u16 Klds[64 * 32];  // 4KB
  int bidx = blockIdx.x;
  int pair = bidx & 63, k0 = (bidx >> 6) * 64;
  int b = pair >> 3;
  int t = threadIdx.x, wave = t >> 6, lane = t & 63;
  int lq = lane & 15, quad = lane >> 4;
  int srow = t >> 2, sseg = t & 3;

  const u16* Qb = QB + (size_t)pair * 1024 * 32;
  const u16* Kb = KB + (size_t)pair * 1024 * 32;
  const float* lvp = linv_ws + (size_t)pair * 1024;

  gl2lds16(Kb + (size_t)(k0 + srow) * 32 + sseg * 8, &Klds[wave * 512]);
  __syncthreads();

  short8 kf[4];
#pragma unroll
  for (int nt = 0; nt < 4; ++nt)
    kf[nt] = *(const short8*)&Klds[(nt * 16 + lq) * 32 + quad * 8];

  const f32x4 zf = (f32x4){0.f, 0.f, 0.f, 0.f};
  float cs[4] = {0.f, 0.f, 0.f, 0.f};
  for (int g = 0; g < 16; ++g) {
    int qg = g * 64 + wave * 16;
    short8 qf = *(const short8*)(Qb + (size_t)(qg + lq) * 32 + quad * 8);
    f32x4 lv = *(const f32x4*)&lvp[qg + quad * 4];
#pragma unroll
    for (int nt = 0; nt < 4; ++nt) {
      f32x4 s = __builtin_amdgcn_mfma_f32_16x16x32_bf16(qf, kf[nt], zf, 0, 0, 0);
      cs[nt] += exp2f(s[0]) * lv[0] + exp2f(s[1]) * lv[1] +
                exp2f(s[2]) * lv[2] + exp2f(s[3]) * lv[3];
    }
  }
#pragma unroll
  for (int nt = 0; nt < 4; ++nt) {
    float v = cs[nt];
    v += __shfl_xor(v, 16);
    v += __shfl_xor(v, 32);
    if (quad == 0)
      atomicAdd(&attn_out[b * 1024 + k0 + nt * 16 + lq], v * (1.f / 8192.f));
  }
}

// ---------------------------------------------------------------------------
// Fused out GEMM + BN + SiLU + residual (R7-exact). Tile 64c x 64s,
// grid (16,4,8)=512. LDS 8KB.
// ---------------------------------------------------------------------------
__global__ __launch_bounds__(256, 4) void fused_out(
    const u16* __restrict__ M2B, const u16* __restrict__ ctxB,
    const float* __restrict__ tgt, const float2* __restrict__ bnpk,
    float* __restrict__ y) {
  __shared__ __align__(16) u16 Al[64 * 32];  // 4KB
  __shared__ __align__(16) u16 Bl[64 * 32];  // 4KB
  int b = blockIdx.z, c0 = blockIdx.y * 64, s0 = blockIdx.x * 64;
  int t = threadIdx.x, wave = t >> 6, lane = t & 63;
  int lq = lane & 15, quad = lane >> 4;
  int srow = t >> 2, sseg = t & 3;
  f32x4 acc[4];
#pragma unroll
  for (int mt = 0; mt < 4; ++mt) acc[mt] = (f32x4){0.f, 0.f, 0.f, 0.f};

  for (int k0 = 0; k0 < 256; k0 += 32) {
    __syncthreads();
    gl2lds16(&M2B[(size_t)(c0 + srow) * 256 + k0 + sseg * 8], &Al[wave * 512]);
    gl2lds16(&ctxB[((size_t)b * 1024 + s0 + srow) * 256 + k0 + sseg * 8],
             &Bl[wave * 512]);
    __syncthreads();
    short8 bf = *(const short8*)&Bl[(wave * 16 + lq) * 32 + quad * 8];
    short8 af[4];
#pragma unroll
    for (int mt = 0; mt < 4; ++mt)
      af[mt] = *(const short8*)&Al[(mt * 16 + lq) * 32 + quad * 8];
#pragma unroll
    for (int mt = 0; mt < 4; ++mt)
      acc[mt] = __builtin_amdgcn_mfma_f32_16x16x32_bf16(af[mt], bf, acc[mt], 0, 0, 0);
  }
  int s = s0 + wave * 16 + lq;
#pragma unroll
  for (int mt = 0; mt < 4; ++mt) {
#pragma unroll
    for (int r = 0; r < 4; ++r) {
      int c = c0 + mt * 16 + quad * 4 + r;
      float2 p = bnpk[c];
      float bn = acc[mt][r] * p.x + p.y;
      float sig = 1.f / (1.f + __expf(-bn));
      size_t idx = ((size_t)b * 256 + c) * 1024 + s;
      y[idx] = tgt[idx] + bn * sig;
    }
  }
}

// ---------------------------------------------------------------------------
extern "C" void kernel_launch(void* const* d_in, const int* in_sizes, int n_in,
                              void* d_out, int out_size, void* d_ws, size_t ws_size,
                              hipStream_t stream) {
  const float* tgt = (const float*)d_in[0];
  const float* src = (const float*)d_in[1];
  const float* kv_w = (const float*)d_in[2];
  const float* in_proj_w = (const float*)d_in[3];
  const float* in_proj_b = (const float*)d_in[4];
  const float* out_proj_w = (const float*)d_in[5];
  const float* out_proj_b = (const float*)d_in[6];
  const float* fuse_w = (const float*)d_in[7];
  const float* bn_gamma = (const float*)d_in[8];
  const float* bn_beta = (const float*)d_in[9];
  const float* bn_mean = (const float*)d_in[10];
  const float* bn_var = (const float*)d_in[11];

  char* W = (char*)d_ws;
  u16* WqB = (u16*)W;                      // 128KB
  u16* WkvB = (u16*)(W + 131072);          // 128KB
  u16* M2B = (u16*)(W + 262144);           // 128KB
  float* qbias = (float*)(W + 393216);     // 1KB
  float2* bnpk = (float2*)(W + 394240);    // 2KB
  u16* tgtT = (u16*)(W + 397312);          // 4MB (B,S,256) bf16
  u16* srcT = tgtT + 2097152;              // 2MB (B,S,128) bf16
  u16* QB = srcT + 1048576;                // 4MB (B,nH,S,hd)
  u16* KB = QB + 2097152;                  // 4MB (B,nH,S,hd)
  u16* VB = KB + 2097152;                  // 4MB (B,E,S)
  u16* ctxB = VB + 2097152;                // 4MB (B,S,E)
  float* linv_ws = (float*)(ctxB + 2097152);  // 256KB (B,nH,S)

  float* y = (float*)d_out;
  float* attn_out = y + 2097152;

  prep_xpose<<<1569, 256, 0, stream>>>(in_proj_w, in_proj_b, kv_w, fuse_w,
                                       out_proj_w, out_proj_b, bn_gamma, bn_beta,
                                       bn_mean, bn_var, tgt, src,
                                       WqB, WkvB, M2B, qbias, bnpk, tgtT, srcT,
                                       attn_out);
  qkv_gemm<<<dim3(8, 12, 8), 256, 0, stream>>>(tgtT, srcT, WqB, WkvB, qbias,
                                               in_proj_b + 256, QB, KB, VB);
  attn_passA<<<1024, 256, 0, stream>>>(QB, KB, VB, ctxB, linv_ws);
  colsum_kernel<<<1024, 256, 0, stream>>>(QB, KB, linv_ws, attn_out);
  fused_out<<<dim3(16, 4, 8), 256, 0, stream>>>(M2B, ctxB, tgt, bnpk, y);
}